// Round 2
// baseline (656.659 us; speedup 1.0000x reference)
//
#include <hip/hip_runtime.h>
#include <hip/hip_bf16.h>

typedef __attribute__((ext_vector_type(8))) short bf16x8;
typedef __attribute__((ext_vector_type(4))) short bf16x4;
typedef __attribute__((ext_vector_type(4))) float f32x4;

#define DEV static __device__ __forceinline__

constexpr int Bc = 4, NQc = 900, Hc = 8, Sc = 21760;
constexpr int M1 = Bc * NQc;           // 3600
constexpr int NQT = (NQc + 63) / 64;   // 15 key/query tiles of 64

DEV short f2bf(float f) {
  union { __hip_bfloat16 h; short s; } u;
  u.h = __float2bfloat16(f);
  return u.s;
}
DEV float bf2f(short s) {
  union { short s; __hip_bfloat16 h; } u;
  u.s = s;
  return __bfloat162float(u.h);
}

// ---------------------------------------------------------------------------
// pack W[K][N] (f32, row-major) -> Wt[N][K] (bf16) for the MFMA gemm (QK/V only)
__global__ __launch_bounds__(256) void pack_w_k(const float* __restrict__ W,
                                                short* __restrict__ Wt,
                                                int K, int N) {
  int t = blockIdx.x * 256 + threadIdx.x;
  int kq = K >> 2;
  int n = t / kq;
  int k4 = (t - n * kq) * 4;
  if (n >= N) return;
  bf16x4 o;
  o[0] = f2bf(W[(size_t)(k4 + 0) * N + n]);
  o[1] = f2bf(W[(size_t)(k4 + 1) * N + n]);
  o[2] = f2bf(W[(size_t)(k4 + 2) * N + n]);
  o[3] = f2bf(W[(size_t)(k4 + 3) * N + n]);
  *(bf16x4*)&Wt[(size_t)n * K + k4] = o;
}

// ---------------------------------------------------------------------------
__global__ __launch_bounds__(256) void add_k(const float* __restrict__ a,
                                             const float* __restrict__ b,
                                             float* __restrict__ o) {
  size_t i = (size_t)(blockIdx.x * 256 + threadIdx.x) * 4;
  float4 x = *(const float4*)(a + i), y = *(const float4*)(b + i);
  *(float4*)(o + i) = make_float4(x.x + y.x, x.y + y.y, x.z + y.z, x.w + y.w);
}

// ---------------------------------------------------------------------------
// bf16 MFMA GEMM (used ONLY for q|k and v projections feeding attention)
template <int ACT, int OUTBF16>
__global__ __launch_bounds__(256) void gemm_k(
    const float* __restrict__ A, const short* __restrict__ Wt,
    const float* __restrict__ bias, void* __restrict__ Cv, int M, int N, int K,
    const unsigned char* __restrict__ rowmask) {
  __shared__ short As[64 * 40];
  __shared__ short Ws[64 * 40];
  const int nb = N >> 6;
  const int bm = blockIdx.x / nb, bn = blockIdx.x % nb;
  const int tid = threadIdx.x;
  const int lane = tid & 63, wave = tid >> 6;
  const int wm = (wave >> 1) * 32, wn = (wave & 1) * 32;
  const int l16 = lane & 15, quad = lane >> 4;
  const int sr = tid >> 2, sk = (tid & 3) * 8;

  f32x4 acc[2][2] = {};
  const int arow = bm * 64 + sr;
  const float* ap = A + (size_t)arow * K + sk;
  const short* wp = Wt + (size_t)(bn * 64 + sr) * K + sk;
  short* asd = &As[sr * 40 + sk];
  short* wsd = &Ws[sr * 40 + sk];

  for (int k0 = 0; k0 < K; k0 += 32) {
    float4 v0, v1;
    if (arow < M) {
      v0 = *(const float4*)(ap + k0);
      v1 = *(const float4*)(ap + k0 + 4);
    } else {
      v0 = make_float4(0.f, 0.f, 0.f, 0.f);
      v1 = v0;
    }
    bf16x8 t;
    t[0] = f2bf(v0.x); t[1] = f2bf(v0.y); t[2] = f2bf(v0.z); t[3] = f2bf(v0.w);
    t[4] = f2bf(v1.x); t[5] = f2bf(v1.y); t[6] = f2bf(v1.z); t[7] = f2bf(v1.w);
    *(bf16x8*)asd = t;
    *(bf16x8*)wsd = *(const bf16x8*)(wp + k0);
    __syncthreads();
    bf16x8 a0 = *(const bf16x8*)&As[(wm + l16) * 40 + quad * 8];
    bf16x8 a1 = *(const bf16x8*)&As[(wm + 16 + l16) * 40 + quad * 8];
    bf16x8 b0 = *(const bf16x8*)&Ws[(wn + l16) * 40 + quad * 8];
    bf16x8 b1 = *(const bf16x8*)&Ws[(wn + 16 + l16) * 40 + quad * 8];
    acc[0][0] = __builtin_amdgcn_mfma_f32_16x16x32_bf16(a0, b0, acc[0][0], 0, 0, 0);
    acc[0][1] = __builtin_amdgcn_mfma_f32_16x16x32_bf16(a0, b1, acc[0][1], 0, 0, 0);
    acc[1][0] = __builtin_amdgcn_mfma_f32_16x16x32_bf16(a1, b0, acc[1][0], 0, 0, 0);
    acc[1][1] = __builtin_amdgcn_mfma_f32_16x16x32_bf16(a1, b1, acc[1][1], 0, 0, 0);
    __syncthreads();
  }
#pragma unroll
  for (int mi = 0; mi < 2; mi++) {
#pragma unroll
    for (int ni = 0; ni < 2; ni++) {
      const int col = bn * 64 + wn + ni * 16 + l16;
      const float bv = bias[col];
#pragma unroll
      for (int r = 0; r < 4; r++) {
        const int m = bm * 64 + wm + mi * 16 + quad * 4 + r;
        if (m < M) {
          float v = acc[mi][ni][r] + bv;
          if (ACT == 1) v = fmaxf(v, 0.f);
          if (rowmask && rowmask[m]) v = 0.f;
          if (OUTBF16)
            ((short*)Cv)[(size_t)m * N + col] = f2bf(v);
          else
            ((float*)Cv)[(size_t)m * N + col] = v;
        }
      }
    }
  }
}

// ---------------------------------------------------------------------------
// Exact fp32 GEMM: C = act(A[M][K] @ W[K][N] + bias). 64x64 tile, 16x16 thr,
// 4x4 per thread, K-tile 16. No bf16 anywhere. W consumed in native layout.
template <int ACT, int OUTBF16>
__global__ __launch_bounds__(256) void gemm32_k(
    const float* __restrict__ A, const float* __restrict__ W,
    const float* __restrict__ bias, void* __restrict__ Cv, int M, int N, int K,
    const unsigned char* __restrict__ rowmask) {
  __shared__ float As[16][64];
  __shared__ float Bs[16][68];
  const int nb = N >> 6;
  const int bm = blockIdx.x / nb, bn = blockIdx.x % nb;
  const int tid = threadIdx.x;
  const int tm = tid >> 4, tn = tid & 15;
  float acc[4][4] = {};

  for (int k0 = 0; k0 < K; k0 += 16) {
    {
      const int m = tid >> 2, kk = (tid & 3) * 4;
      const int row = bm * 64 + m;
      float4 v = (row < M) ? *(const float4*)(A + (size_t)row * K + k0 + kk)
                           : make_float4(0.f, 0.f, 0.f, 0.f);
      As[kk + 0][m] = v.x; As[kk + 1][m] = v.y;
      As[kk + 2][m] = v.z; As[kk + 3][m] = v.w;
    }
    {
      const int kk = tid >> 4, n = (tid & 15) * 4;
      float4 v = *(const float4*)(W + (size_t)(k0 + kk) * N + bn * 64 + n);
      *(float4*)&Bs[kk][n] = v;
    }
    __syncthreads();
#pragma unroll
    for (int kk = 0; kk < 16; kk++) {
      float a[4], b[4];
#pragma unroll
      for (int i = 0; i < 4; i++) a[i] = As[kk][tm * 4 + i];
#pragma unroll
      for (int j = 0; j < 4; j++) b[j] = Bs[kk][tn * 4 + j];
#pragma unroll
      for (int i = 0; i < 4; i++)
#pragma unroll
        for (int j = 0; j < 4; j++) acc[i][j] = fmaf(a[i], b[j], acc[i][j]);
    }
    __syncthreads();
  }
#pragma unroll
  for (int i = 0; i < 4; i++) {
    const int row = bm * 64 + tm * 4 + i;
    if (row >= M) continue;
    const bool masked = rowmask && rowmask[row];
#pragma unroll
    for (int j = 0; j < 4; j++) {
      const int col = bn * 64 + tn * 4 + j;
      float v = acc[i][j] + bias[col];
      if (ACT == 1) v = fmaxf(v, 0.f);
      if (masked) v = 0.f;
      if (OUTBF16)
        ((short*)Cv)[(size_t)row * N + col] = f2bf(v);
      else
        ((float*)Cv)[(size_t)row * N + col] = v;
    }
  }
}

// ---------------------------------------------------------------------------
// Flash-style MFMA self-attention (unchanged; errors here are attenuated by
// out_proj to <0.02 at the output, provably not the absmax culprit).
__global__ __launch_bounds__(256) void attn_k(const float* __restrict__ qk,
                                              const float* __restrict__ vbuf,
                                              float* __restrict__ sa) {
  __shared__ short Vt[32 * 72];
  __shared__ short Pb[4][16 * 72];
  const int bid = blockIdx.x;
  const int qt = bid % NQT, bh = bid / NQT;
  const int b = bh >> 3, h = bh & 7;
  const int tid = threadIdx.x, lane = tid & 63, wave = tid >> 6;
  const int l16 = lane & 15, quad = lane >> 4;

  const int q_local = qt * 64 + wave * 16 + l16;
  const int qrow = b * NQc + min(q_local, NQc - 1);
  const float scale = 0.17677669529663687f;
  bf16x8 qf;
  {
    const float* qp = qk + (size_t)qrow * 512 + h * 32 + quad * 8;
    float4 v0 = *(const float4*)qp, v1 = *(const float4*)(qp + 4);
    qf[0] = f2bf(v0.x * scale); qf[1] = f2bf(v0.y * scale);
    qf[2] = f2bf(v0.z * scale); qf[3] = f2bf(v0.w * scale);
    qf[4] = f2bf(v1.x * scale); qf[5] = f2bf(v1.y * scale);
    qf[6] = f2bf(v1.z * scale); qf[7] = f2bf(v1.w * scale);
  }
  f32x4 o0 = {}, o1 = {};
  float mrun[4] = {-1e30f, -1e30f, -1e30f, -1e30f};
  float lrun[4] = {0.f, 0.f, 0.f, 0.f};

  for (int kt = 0; kt < NQT; kt++) {
    const int k0 = kt * 64;
    __syncthreads();
#pragma unroll
    for (int i = 0; i < 8; i++) {
      int kk = i * 8 + (tid >> 5);
      int ch = tid & 31;
      int key = k0 + kk;
      float v = (key < NQc) ? vbuf[(size_t)(b * NQc + key) * 256 + h * 32 + ch] : 0.f;
      Vt[ch * 72 + kk] = f2bf(v);
    }
    __syncthreads();

    f32x4 s[4];
#pragma unroll
    for (int st = 0; st < 4; st++) {
      const int key = k0 + st * 16 + l16;
      const int krow = b * NQc + min(key, NQc - 1);
      const float* kp = qk + (size_t)krow * 512 + 256 + h * 32 + quad * 8;
      float4 v0 = *(const float4*)kp, v1 = *(const float4*)(kp + 4);
      bf16x8 kf;
      kf[0] = f2bf(v0.x); kf[1] = f2bf(v0.y); kf[2] = f2bf(v0.z); kf[3] = f2bf(v0.w);
      kf[4] = f2bf(v1.x); kf[5] = f2bf(v1.y); kf[6] = f2bf(v1.z); kf[7] = f2bf(v1.w);
      f32x4 z = {};
      s[st] = __builtin_amdgcn_mfma_f32_16x16x32_bf16(qf, kf, z, 0, 0, 0);
      if (key >= NQc) { s[st][0] = -1e30f; s[st][1] = -1e30f; s[st][2] = -1e30f; s[st][3] = -1e30f; }
    }
    float mnew[4], alpha[4];
#pragma unroll
    for (int r = 0; r < 4; r++) {
      float mx = fmaxf(fmaxf(s[0][r], s[1][r]), fmaxf(s[2][r], s[3][r]));
#pragma unroll
      for (int d = 1; d < 16; d <<= 1) mx = fmaxf(mx, __shfl_xor(mx, d));
      mnew[r] = fmaxf(mrun[r], mx);
      alpha[r] = __expf(mrun[r] - mnew[r]);
      mrun[r] = mnew[r];
    }
    float tsum[4] = {0.f, 0.f, 0.f, 0.f};
#pragma unroll
    for (int st = 0; st < 4; st++) {
#pragma unroll
      for (int r = 0; r < 4; r++) {
        float p = __expf(s[st][r] - mnew[r]);
        s[st][r] = p;
        tsum[r] += p;
      }
    }
#pragma unroll
    for (int r = 0; r < 4; r++) {
      float t = tsum[r];
#pragma unroll
      for (int d = 1; d < 16; d <<= 1) t += __shfl_xor(t, d);
      lrun[r] = lrun[r] * alpha[r] + t;
      o0[r] *= alpha[r];
      o1[r] *= alpha[r];
    }
    short* pw = Pb[wave];
#pragma unroll
    for (int st = 0; st < 4; st++)
#pragma unroll
      for (int r = 0; r < 4; r++)
        pw[(quad * 4 + r) * 72 + st * 16 + l16] = f2bf(s[st][r]);
#pragma unroll
    for (int c = 0; c < 2; c++) {
      bf16x8 pf = *(const bf16x8*)&pw[l16 * 72 + c * 32 + quad * 8];
      bf16x8 vf0 = *(const bf16x8*)&Vt[l16 * 72 + c * 32 + quad * 8];
      bf16x8 vf1 = *(const bf16x8*)&Vt[(16 + l16) * 72 + c * 32 + quad * 8];
      o0 = __builtin_amdgcn_mfma_f32_16x16x32_bf16(pf, vf0, o0, 0, 0, 0);
      o1 = __builtin_amdgcn_mfma_f32_16x16x32_bf16(pf, vf1, o1, 0, 0, 0);
    }
  }
#pragma unroll
  for (int r = 0; r < 4; r++) {
    const int q = qt * 64 + wave * 16 + quad * 4 + r;
    if (q < NQc) {
      const float inv = 1.f / lrun[r];
      sa[(size_t)(b * NQc + q) * 256 + h * 32 + l16] = o0[r] * inv;
      sa[(size_t)(b * NQc + q) * 256 + h * 32 + 16 + l16] = o1[r] * inv;
    }
  }
}

// ---------------------------------------------------------------------------
__global__ __launch_bounds__(256) void ln_k(
    const float* __restrict__ resid, const float* __restrict__ x,
    const float* __restrict__ g, const float* __restrict__ bta,
    float* __restrict__ out, const float* __restrict__ qpos,
    float* __restrict__ out2) {
  const int row = blockIdx.x * 4 + (threadIdx.x >> 6);
  const int lane = threadIdx.x & 63;
  const size_t base = (size_t)row * 256 + lane * 4;
  float4 rv = *(const float4*)(resid + base);
  float4 xv = *(const float4*)(x + base);
  float4 v = make_float4(rv.x + xv.x, rv.y + xv.y, rv.z + xv.z, rv.w + xv.w);
  float sum = v.x + v.y + v.z + v.w;
#pragma unroll
  for (int d = 1; d < 64; d <<= 1) sum += __shfl_xor(sum, d);
  const float mean = sum * (1.f / 256.f);
  float a0 = v.x - mean, a1 = v.y - mean, a2 = v.z - mean, a3 = v.w - mean;
  float vs = a0 * a0 + a1 * a1 + a2 * a2 + a3 * a3;
#pragma unroll
  for (int d = 1; d < 64; d <<= 1) vs += __shfl_xor(vs, d);
  const float rstd = rsqrtf(vs * (1.f / 256.f) + 1e-5f);
  float4 gv = *(const float4*)(g + lane * 4);
  float4 bv = *(const float4*)(bta + lane * 4);
  float4 o = make_float4(a0 * rstd * gv.x + bv.x, a1 * rstd * gv.y + bv.y,
                         a2 * rstd * gv.z + bv.z, a3 * rstd * gv.w + bv.w);
  *(float4*)(out + base) = o;
  if (out2) {
    float4 qv = *(const float4*)(qpos + base);
    *(float4*)(out2 + base) = make_float4(o.x + qv.x, o.y + qv.y, o.z + qv.z, o.w + qv.w);
  }
}

// ---------------------------------------------------------------------------
__global__ __launch_bounds__(256) void sample_k(
    const float* __restrict__ awlin, const float* __restrict__ off,
    const float* __restrict__ refp, const short* __restrict__ value,
    float* __restrict__ accout) {
  const int wid = blockIdx.x * 4 + (threadIdx.x >> 6);
  const int lane = threadIdx.x & 63;
  const int bq = wid >> 3, h = wid & 7;
  const int b = bq / NQc;
  const int l16 = lane & 15;

  float wraw = awlin[(size_t)bq * 128 + h * 16 + l16];
  float mx = wraw;
#pragma unroll
  for (int d = 1; d < 16; d <<= 1) mx = fmaxf(mx, __shfl_xor(mx, d));
  float e = __expf(wraw - mx), ssum = e;
#pragma unroll
  for (int d = 1; d < 16; d <<= 1) ssum += __shfl_xor(ssum, d);
  const float wnorm = e / ssum;

  const int ch = lane & 31, sub = lane >> 5;
  float facc = 0.f;
#pragma unroll
  for (int it = 0; it < 8; it++) {
    const int pt = it * 2 + sub;
    const float w = __shfl(wnorm, pt);
    const int l = pt >> 2;
    const int W = 128 >> l;
    const int start = (l == 0) ? 0 : (l == 1) ? 16384 : (l == 2) ? 20480 : 21504;
    const float offx = off[(size_t)bq * 256 + h * 32 + pt * 2];
    const float offy = off[(size_t)bq * 256 + h * 32 + pt * 2 + 1];
    const float rx = refp[(size_t)bq * 8 + l * 2];
    const float ry = refp[(size_t)bq * 8 + l * 2 + 1];
    const float x = rx * (float)W + offx - 0.5f;
    const float y = ry * (float)W + offy - 0.5f;
    const float x0f = floorf(x), y0f = floorf(y);
    const float wx = x - x0f, wy = y - y0f;
    const int x0 = (int)x0f, y0 = (int)y0f;
    const short* vb = value + ((size_t)b * Sc + start) * 256 + h * 32 + ch;
#pragma unroll
    for (int c4 = 0; c4 < 4; c4++) {
      const int dx = c4 & 1, dy = c4 >> 1;
      const int xi = x0 + dx, yi = y0 + dy;
      const bool valid = (xi >= 0) && (xi < W) && (yi >= 0) && (yi < W);
      const int xc = min(max(xi, 0), W - 1);
      const int yc = min(max(yi, 0), W - 1);
      const float gvv = bf2f(vb[(size_t)(yc * W + xc) * 256]);
      const float ww = (dx ? wx : 1.f - wx) * (dy ? wy : 1.f - wy);
      facc += valid ? w * ww * gvv : 0.f;
    }
  }
  facc += __shfl_xor(facc, 32);
  if (lane < 32) accout[(size_t)bq * 256 + h * 32 + ch] = facc;
}

// ---------------------------------------------------------------------------
extern "C" void kernel_launch(void* const* d_in, const int* in_sizes, int n_in,
                              void* d_out, int out_size, void* d_ws,
                              size_t ws_size, hipStream_t stream) {
  const float* tgt = (const float*)d_in[0];
  const float* query_pos = (const float*)d_in[1];
  const float* refp = (const float*)d_in[2];
  const float* memory = (const float*)d_in[3];
  const float* in_proj_w = (const float*)d_in[4];
  const float* in_proj_b = (const float*)d_in[5];
  const float* out_proj_w = (const float*)d_in[6];
  const float* out_proj_b = (const float*)d_in[7];
  const float* ln1_g = (const float*)d_in[8];
  const float* ln1_b = (const float*)d_in[9];
  const float* ln2_g = (const float*)d_in[10];
  const float* ln2_b = (const float*)d_in[11];
  const float* ln3_g = (const float*)d_in[12];
  const float* ln3_b = (const float*)d_in[13];
  const float* vproj_w = (const float*)d_in[14];
  const float* vproj_b = (const float*)d_in[15];
  const float* off_w = (const float*)d_in[16];
  const float* off_b = (const float*)d_in[17];
  const float* aw_w = (const float*)d_in[18];
  const float* aw_b = (const float*)d_in[19];
  const float* oproj_w = (const float*)d_in[20];
  const float* oproj_b = (const float*)d_in[21];
  const float* lin1_w = (const float*)d_in[22];
  const float* lin1_b = (const float*)d_in[23];
  const float* lin2_w = (const float*)d_in[24];
  const float* lin2_b = (const float*)d_in[25];
  const unsigned char* mem_mask = (const unsigned char*)d_in[27];
  float* out = (float*)d_out;

  float* ws = (float*)d_ws;
  float* qp = ws + 0;
  float* qkbuf = ws + 921600;
  float* vbuf = ws + 2764800;
  float* sa = ws + 3686400;
  float* tmp = ws + 4608000;
  float* tgt2 = ws + 5529600;
  float* query = ws + 6451200;
  float* offb = ws + 7372800;
  float* awlin = ws + 8294400;
  float* accb = ws + 8755200;
  float* tgt3 = ws + 9676800;
  float* ff1 = ws + 10598400;
  short* valueBf = (short*)(ws + 14284800);  // 22282240 shorts (bf16)
  short* inprojT = valueBf + 22282240;       // [768][256] bf16

  pack_w_k<<<192, 256, 0, stream>>>(in_proj_w, inprojT, 256, 768);
  add_k<<<900, 256, 0, stream>>>(tgt, query_pos, qp);

  // q|k and v projections (attention-only consumers): bf16 MFMA
  gemm_k<0, 0><<<57 * 8, 256, 0, stream>>>(qp, inprojT, in_proj_b, qkbuf, M1, 512, 256, nullptr);
  gemm_k<0, 0><<<57 * 4, 256, 0, stream>>>(tgt, inprojT + 512 * 256, in_proj_b + 512, vbuf, M1, 256, 256, nullptr);
  attn_k<<<Bc * Hc * NQT, 256, 0, stream>>>(qkbuf, vbuf, sa);

  // everything feeding the residual stream: exact fp32
  gemm32_k<0, 0><<<57 * 4, 256, 0, stream>>>(sa, out_proj_w, out_proj_b, tmp, M1, 256, 256, nullptr);
  ln_k<<<900, 256, 0, stream>>>(tgt, tmp, ln2_g, ln2_b, tgt2, query_pos, query);
  gemm32_k<0, 1><<<1360 * 4, 256, 0, stream>>>(memory, vproj_w, vproj_b, valueBf, Bc * Sc, 256, 256, mem_mask);
  gemm32_k<0, 0><<<57 * 4, 256, 0, stream>>>(query, off_w, off_b, offb, M1, 256, 256, nullptr);
  gemm32_k<0, 0><<<57 * 2, 256, 0, stream>>>(query, aw_w, aw_b, awlin, M1, 128, 256, nullptr);
  sample_k<<<Bc * NQc * Hc / 4, 256, 0, stream>>>(awlin, offb, refp, valueBf, accb);
  gemm32_k<0, 0><<<57 * 4, 256, 0, stream>>>(accb, oproj_w, oproj_b, tmp, M1, 256, 256, nullptr);
  ln_k<<<900, 256, 0, stream>>>(tgt2, tmp, ln1_g, ln1_b, tgt3, nullptr, nullptr);
  gemm32_k<1, 0><<<57 * 16, 256, 0, stream>>>(tgt3, lin1_w, lin1_b, ff1, M1, 1024, 256, nullptr);
  gemm32_k<0, 0><<<57 * 4, 256, 0, stream>>>(ff1, lin2_w, lin2_b, tmp, M1, 256, 1024, nullptr);
  ln_k<<<900, 256, 0, stream>>>(tgt3, tmp, ln3_g, ln3_b, out, nullptr, nullptr);
}

// Round 3
// 495.222 us; speedup vs baseline: 1.3260x; 1.3260x over previous
//
#include <hip/hip_runtime.h>
#include <hip/hip_bf16.h>

typedef __attribute__((ext_vector_type(8))) short bf16x8;
typedef __attribute__((ext_vector_type(4))) short bf16x4;
typedef __attribute__((ext_vector_type(4))) float f32x4;

#define DEV static __device__ __forceinline__

constexpr int Bc = 4, NQc = 900, Hc = 8, Sc = 21760;
constexpr int M1 = Bc * NQc;           // 3600
constexpr int NQT = (NQc + 63) / 64;   // 15 key/query tiles of 64

DEV short f2bf(float f) {
  union { __hip_bfloat16 h; short s; } u;
  u.h = __float2bfloat16(f);
  return u.s;
}
DEV float bf2f(short s) {
  union { short s; __hip_bfloat16 h; } u;
  u.s = s;
  return __bfloat162float(u.h);
}

// ---------------------------------------------------------------------------
// pack W[K][N] (f32, row-major) -> Wt[N][K] (bf16)
__global__ __launch_bounds__(256) void pack_w_k(const float* __restrict__ W,
                                                short* __restrict__ Wt,
                                                int K, int N) {
  int t = blockIdx.x * 256 + threadIdx.x;
  int kq = K >> 2;
  int n = t / kq;
  int k4 = (t - n * kq) * 4;
  if (n >= N) return;
  bf16x4 o;
  o[0] = f2bf(W[(size_t)(k4 + 0) * N + n]);
  o[1] = f2bf(W[(size_t)(k4 + 1) * N + n]);
  o[2] = f2bf(W[(size_t)(k4 + 2) * N + n]);
  o[3] = f2bf(W[(size_t)(k4 + 3) * N + n]);
  *(bf16x4*)&Wt[(size_t)n * K + k4] = o;
}

// ---------------------------------------------------------------------------
__global__ __launch_bounds__(256) void add_k(const float* __restrict__ a,
                                             const float* __restrict__ b,
                                             float* __restrict__ o) {
  size_t i = (size_t)(blockIdx.x * 256 + threadIdx.x) * 4;
  float4 x = *(const float4*)(a + i), y = *(const float4*)(b + i);
  *(float4*)(o + i) = make_float4(x.x + y.x, x.y + y.y, x.z + y.z, x.w + y.w);
}

// ---------------------------------------------------------------------------
// bf16 MFMA GEMM: C = act(A[M][K]@W + bias). A fp32 row-major, Wt bf16 [N][K].
// 64x64 tile, 4 waves 2x2, each wave 32x32 via 2x2 mfma_16x16x32.
template <int ACT, int OUTBF16>
__global__ __launch_bounds__(256) void gemm_k(
    const float* __restrict__ A, const short* __restrict__ Wt,
    const float* __restrict__ bias, void* __restrict__ Cv, int M, int N, int K,
    const unsigned char* __restrict__ rowmask) {
  __shared__ short As[64 * 40];
  __shared__ short Ws[64 * 40];
  const int nb = N >> 6;
  const int bm = blockIdx.x / nb, bn = blockIdx.x % nb;
  const int tid = threadIdx.x;
  const int lane = tid & 63, wave = tid >> 6;
  const int wm = (wave >> 1) * 32, wn = (wave & 1) * 32;
  const int l16 = lane & 15, quad = lane >> 4;
  const int sr = tid >> 2, sk = (tid & 3) * 8;

  f32x4 acc[2][2] = {};
  const int arow = bm * 64 + sr;
  const float* ap = A + (size_t)arow * K + sk;
  const short* wp = Wt + (size_t)(bn * 64 + sr) * K + sk;
  short* asd = &As[sr * 40 + sk];
  short* wsd = &Ws[sr * 40 + sk];

  for (int k0 = 0; k0 < K; k0 += 32) {
    float4 v0, v1;
    if (arow < M) {
      v0 = *(const float4*)(ap + k0);
      v1 = *(const float4*)(ap + k0 + 4);
    } else {
      v0 = make_float4(0.f, 0.f, 0.f, 0.f);
      v1 = v0;
    }
    bf16x8 t;
    t[0] = f2bf(v0.x); t[1] = f2bf(v0.y); t[2] = f2bf(v0.z); t[3] = f2bf(v0.w);
    t[4] = f2bf(v1.x); t[5] = f2bf(v1.y); t[6] = f2bf(v1.z); t[7] = f2bf(v1.w);
    *(bf16x8*)asd = t;
    *(bf16x8*)wsd = *(const bf16x8*)(wp + k0);
    __syncthreads();
    bf16x8 a0 = *(const bf16x8*)&As[(wm + l16) * 40 + quad * 8];
    bf16x8 a1 = *(const bf16x8*)&As[(wm + 16 + l16) * 40 + quad * 8];
    bf16x8 b0 = *(const bf16x8*)&Ws[(wn + l16) * 40 + quad * 8];
    bf16x8 b1 = *(const bf16x8*)&Ws[(wn + 16 + l16) * 40 + quad * 8];
    acc[0][0] = __builtin_amdgcn_mfma_f32_16x16x32_bf16(a0, b0, acc[0][0], 0, 0, 0);
    acc[0][1] = __builtin_amdgcn_mfma_f32_16x16x32_bf16(a0, b1, acc[0][1], 0, 0, 0);
    acc[1][0] = __builtin_amdgcn_mfma_f32_16x16x32_bf16(a1, b0, acc[1][0], 0, 0, 0);
    acc[1][1] = __builtin_amdgcn_mfma_f32_16x16x32_bf16(a1, b1, acc[1][1], 0, 0, 0);
    __syncthreads();
  }
#pragma unroll
  for (int mi = 0; mi < 2; mi++) {
#pragma unroll
    for (int ni = 0; ni < 2; ni++) {
      const int col = bn * 64 + wn + ni * 16 + l16;
      const float bv = bias[col];
#pragma unroll
      for (int r = 0; r < 4; r++) {
        const int m = bm * 64 + wm + mi * 16 + quad * 4 + r;
        if (m < M) {
          float v = acc[mi][ni][r] + bv;
          if (ACT == 1) v = fmaxf(v, 0.f);
          if (rowmask && rowmask[m]) v = 0.f;
          if (OUTBF16)
            ((short*)Cv)[(size_t)m * N + col] = f2bf(v);
          else
            ((float*)Cv)[(size_t)m * N + col] = v;
        }
      }
    }
  }
}

// ---------------------------------------------------------------------------
// Exact fp32 GEMM (off/aw projections only — sampler-amplified precision path)
template <int ACT, int OUTBF16>
__global__ __launch_bounds__(256) void gemm32_k(
    const float* __restrict__ A, const float* __restrict__ W,
    const float* __restrict__ bias, void* __restrict__ Cv, int M, int N, int K,
    const unsigned char* __restrict__ rowmask) {
  __shared__ float As[16][64];
  __shared__ float Bs[16][68];
  const int nb = N >> 6;
  const int bm = blockIdx.x / nb, bn = blockIdx.x % nb;
  const int tid = threadIdx.x;
  const int tm = tid >> 4, tn = tid & 15;
  float acc[4][4] = {};

  for (int k0 = 0; k0 < K; k0 += 16) {
    {
      const int m = tid >> 2, kk = (tid & 3) * 4;
      const int row = bm * 64 + m;
      float4 v = (row < M) ? *(const float4*)(A + (size_t)row * K + k0 + kk)
                           : make_float4(0.f, 0.f, 0.f, 0.f);
      As[kk + 0][m] = v.x; As[kk + 1][m] = v.y;
      As[kk + 2][m] = v.z; As[kk + 3][m] = v.w;
    }
    {
      const int kk = tid >> 4, n = (tid & 15) * 4;
      float4 v = *(const float4*)(W + (size_t)(k0 + kk) * N + bn * 64 + n);
      *(float4*)&Bs[kk][n] = v;
    }
    __syncthreads();
#pragma unroll
    for (int kk = 0; kk < 16; kk++) {
      float a[4], b[4];
#pragma unroll
      for (int i = 0; i < 4; i++) a[i] = As[kk][tm * 4 + i];
#pragma unroll
      for (int j = 0; j < 4; j++) b[j] = Bs[kk][tn * 4 + j];
#pragma unroll
      for (int i = 0; i < 4; i++)
#pragma unroll
        for (int j = 0; j < 4; j++) acc[i][j] = fmaf(a[i], b[j], acc[i][j]);
    }
    __syncthreads();
  }
#pragma unroll
  for (int i = 0; i < 4; i++) {
    const int row = bm * 64 + tm * 4 + i;
    if (row >= M) continue;
    const bool masked = rowmask && rowmask[row];
#pragma unroll
    for (int j = 0; j < 4; j++) {
      const int col = bn * 64 + tn * 4 + j;
      float v = acc[i][j] + bias[col];
      if (ACT == 1) v = fmaxf(v, 0.f);
      if (masked) v = 0.f;
      if (OUTBF16)
        ((short*)Cv)[(size_t)row * N + col] = f2bf(v);
      else
        ((float*)Cv)[(size_t)row * N + col] = v;
    }
  }
}

// ---------------------------------------------------------------------------
__global__ __launch_bounds__(256) void attn_k(const float* __restrict__ qk,
                                              const float* __restrict__ vbuf,
                                              float* __restrict__ sa) {
  __shared__ short Vt[32 * 72];
  __shared__ short Pb[4][16 * 72];
  const int bid = blockIdx.x;
  const int qt = bid % NQT, bh = bid / NQT;
  const int b = bh >> 3, h = bh & 7;
  const int tid = threadIdx.x, lane = tid & 63, wave = tid >> 6;
  const int l16 = lane & 15, quad = lane >> 4;

  const int q_local = qt * 64 + wave * 16 + l16;
  const int qrow = b * NQc + min(q_local, NQc - 1);
  const float scale = 0.17677669529663687f;
  bf16x8 qf;
  {
    const float* qp = qk + (size_t)qrow * 512 + h * 32 + quad * 8;
    float4 v0 = *(const float4*)qp, v1 = *(const float4*)(qp + 4);
    qf[0] = f2bf(v0.x * scale); qf[1] = f2bf(v0.y * scale);
    qf[2] = f2bf(v0.z * scale); qf[3] = f2bf(v0.w * scale);
    qf[4] = f2bf(v1.x * scale); qf[5] = f2bf(v1.y * scale);
    qf[6] = f2bf(v1.z * scale); qf[7] = f2bf(v1.w * scale);
  }
  f32x4 o0 = {}, o1 = {};
  float mrun[4] = {-1e30f, -1e30f, -1e30f, -1e30f};
  float lrun[4] = {0.f, 0.f, 0.f, 0.f};

  for (int kt = 0; kt < NQT; kt++) {
    const int k0 = kt * 64;
    __syncthreads();
#pragma unroll
    for (int i = 0; i < 8; i++) {
      int kk = i * 8 + (tid >> 5);
      int ch = tid & 31;
      int key = k0 + kk;
      float v = (key < NQc) ? vbuf[(size_t)(b * NQc + key) * 256 + h * 32 + ch] : 0.f;
      Vt[ch * 72 + kk] = f2bf(v);
    }
    __syncthreads();

    f32x4 s[4];
#pragma unroll
    for (int st = 0; st < 4; st++) {
      const int key = k0 + st * 16 + l16;
      const int krow = b * NQc + min(key, NQc - 1);
      const float* kp = qk + (size_t)krow * 512 + 256 + h * 32 + quad * 8;
      float4 v0 = *(const float4*)kp, v1 = *(const float4*)(kp + 4);
      bf16x8 kf;
      kf[0] = f2bf(v0.x); kf[1] = f2bf(v0.y); kf[2] = f2bf(v0.z); kf[3] = f2bf(v0.w);
      kf[4] = f2bf(v1.x); kf[5] = f2bf(v1.y); kf[6] = f2bf(v1.z); kf[7] = f2bf(v1.w);
      f32x4 z = {};
      s[st] = __builtin_amdgcn_mfma_f32_16x16x32_bf16(qf, kf, z, 0, 0, 0);
      if (key >= NQc) { s[st][0] = -1e30f; s[st][1] = -1e30f; s[st][2] = -1e30f; s[st][3] = -1e30f; }
    }
    float mnew[4], alpha[4];
#pragma unroll
    for (int r = 0; r < 4; r++) {
      float mx = fmaxf(fmaxf(s[0][r], s[1][r]), fmaxf(s[2][r], s[3][r]));
#pragma unroll
      for (int d = 1; d < 16; d <<= 1) mx = fmaxf(mx, __shfl_xor(mx, d));
      mnew[r] = fmaxf(mrun[r], mx);
      alpha[r] = __expf(mrun[r] - mnew[r]);
      mrun[r] = mnew[r];
    }
    float tsum[4] = {0.f, 0.f, 0.f, 0.f};
#pragma unroll
    for (int st = 0; st < 4; st++) {
#pragma unroll
      for (int r = 0; r < 4; r++) {
        float p = __expf(s[st][r] - mnew[r]);
        s[st][r] = p;
        tsum[r] += p;
      }
    }
#pragma unroll
    for (int r = 0; r < 4; r++) {
      float t = tsum[r];
#pragma unroll
      for (int d = 1; d < 16; d <<= 1) t += __shfl_xor(t, d);
      lrun[r] = lrun[r] * alpha[r] + t;
      o0[r] *= alpha[r];
      o1[r] *= alpha[r];
    }
    short* pw = Pb[wave];
#pragma unroll
    for (int st = 0; st < 4; st++)
#pragma unroll
      for (int r = 0; r < 4; r++)
        pw[(quad * 4 + r) * 72 + st * 16 + l16] = f2bf(s[st][r]);
#pragma unroll
    for (int c = 0; c < 2; c++) {
      bf16x8 pf = *(const bf16x8*)&pw[l16 * 72 + c * 32 + quad * 8];
      bf16x8 vf0 = *(const bf16x8*)&Vt[l16 * 72 + c * 32 + quad * 8];
      bf16x8 vf1 = *(const bf16x8*)&Vt[(16 + l16) * 72 + c * 32 + quad * 8];
      o0 = __builtin_amdgcn_mfma_f32_16x16x32_bf16(pf, vf0, o0, 0, 0, 0);
      o1 = __builtin_amdgcn_mfma_f32_16x16x32_bf16(pf, vf1, o1, 0, 0, 0);
    }
  }
#pragma unroll
  for (int r = 0; r < 4; r++) {
    const int q = qt * 64 + wave * 16 + quad * 4 + r;
    if (q < NQc) {
      const float inv = 1.f / lrun[r];
      sa[(size_t)(b * NQc + q) * 256 + h * 32 + l16] = o0[r] * inv;
      sa[(size_t)(b * NQc + q) * 256 + h * 32 + 16 + l16] = o1[r] * inv;
    }
  }
}

// ---------------------------------------------------------------------------
__global__ __launch_bounds__(256) void ln_k(
    const float* __restrict__ resid, const float* __restrict__ x,
    const float* __restrict__ g, const float* __restrict__ bta,
    float* __restrict__ out, const float* __restrict__ qpos,
    float* __restrict__ out2) {
  const int row = blockIdx.x * 4 + (threadIdx.x >> 6);
  const int lane = threadIdx.x & 63;
  const size_t base = (size_t)row * 256 + lane * 4;
  float4 rv = *(const float4*)(resid + base);
  float4 xv = *(const float4*)(x + base);
  float4 v = make_float4(rv.x + xv.x, rv.y + xv.y, rv.z + xv.z, rv.w + xv.w);
  float sum = v.x + v.y + v.z + v.w;
#pragma unroll
  for (int d = 1; d < 64; d <<= 1) sum += __shfl_xor(sum, d);
  const float mean = sum * (1.f / 256.f);
  float a0 = v.x - mean, a1 = v.y - mean, a2 = v.z - mean, a3 = v.w - mean;
  float vs = a0 * a0 + a1 * a1 + a2 * a2 + a3 * a3;
#pragma unroll
  for (int d = 1; d < 64; d <<= 1) vs += __shfl_xor(vs, d);
  const float rstd = rsqrtf(vs * (1.f / 256.f) + 1e-5f);
  float4 gv = *(const float4*)(g + lane * 4);
  float4 bv = *(const float4*)(bta + lane * 4);
  float4 o = make_float4(a0 * rstd * gv.x + bv.x, a1 * rstd * gv.y + bv.y,
                         a2 * rstd * gv.z + bv.z, a3 * rstd * gv.w + bv.w);
  *(float4*)(out + base) = o;
  if (out2) {
    float4 qv = *(const float4*)(qpos + base);
    *(float4*)(out2 + base) = make_float4(o.x + qv.x, o.y + qv.y, o.z + qv.z, o.w + qv.w);
  }
}

// ---------------------------------------------------------------------------
__global__ __launch_bounds__(256) void sample_k(
    const float* __restrict__ awlin, const float* __restrict__ off,
    const float* __restrict__ refp, const short* __restrict__ value,
    float* __restrict__ accout) {
  const int wid = blockIdx.x * 4 + (threadIdx.x >> 6);
  const int lane = threadIdx.x & 63;
  const int bq = wid >> 3, h = wid & 7;
  const int b = bq / NQc;
  const int l16 = lane & 15;

  float wraw = awlin[(size_t)bq * 128 + h * 16 + l16];
  float mx = wraw;
#pragma unroll
  for (int d = 1; d < 16; d <<= 1) mx = fmaxf(mx, __shfl_xor(mx, d));
  float e = __expf(wraw - mx), ssum = e;
#pragma unroll
  for (int d = 1; d < 16; d <<= 1) ssum += __shfl_xor(ssum, d);
  const float wnorm = e / ssum;

  const int ch = lane & 31, sub = lane >> 5;
  float facc = 0.f;
#pragma unroll
  for (int it = 0; it < 8; it++) {
    const int pt = it * 2 + sub;
    const float w = __shfl(wnorm, pt);
    const int l = pt >> 2;
    const int W = 128 >> l;
    const int start = (l == 0) ? 0 : (l == 1) ? 16384 : (l == 2) ? 20480 : 21504;
    const float offx = off[(size_t)bq * 256 + h * 32 + pt * 2];
    const float offy = off[(size_t)bq * 256 + h * 32 + pt * 2 + 1];
    const float rx = refp[(size_t)bq * 8 + l * 2];
    const float ry = refp[(size_t)bq * 8 + l * 2 + 1];
    const float x = rx * (float)W + offx - 0.5f;
    const float y = ry * (float)W + offy - 0.5f;
    const float x0f = floorf(x), y0f = floorf(y);
    const float wx = x - x0f, wy = y - y0f;
    const int x0 = (int)x0f, y0 = (int)y0f;
    const short* vb = value + ((size_t)b * Sc + start) * 256 + h * 32 + ch;
#pragma unroll
    for (int c4 = 0; c4 < 4; c4++) {
      const int dx = c4 & 1, dy = c4 >> 1;
      const int xi = x0 + dx, yi = y0 + dy;
      const bool valid = (xi >= 0) && (xi < W) && (yi >= 0) && (yi < W);
      const int xc = min(max(xi, 0), W - 1);
      const int yc = min(max(yi, 0), W - 1);
      const float gvv = bf2f(vb[(size_t)(yc * W + xc) * 256]);
      const float ww = (dx ? wx : 1.f - wx) * (dy ? wy : 1.f - wy);
      facc += valid ? w * ww * gvv : 0.f;
    }
  }
  facc += __shfl_xor(facc, 32);
  if (lane < 32) accout[(size_t)bq * 256 + h * 32 + ch] = facc;
}

// ---------------------------------------------------------------------------
extern "C" void kernel_launch(void* const* d_in, const int* in_sizes, int n_in,
                              void* d_out, int out_size, void* d_ws,
                              size_t ws_size, hipStream_t stream) {
  const float* tgt = (const float*)d_in[0];
  const float* query_pos = (const float*)d_in[1];
  const float* refp = (const float*)d_in[2];
  const float* memory = (const float*)d_in[3];
  const float* in_proj_w = (const float*)d_in[4];
  const float* in_proj_b = (const float*)d_in[5];
  const float* out_proj_w = (const float*)d_in[6];
  const float* out_proj_b = (const float*)d_in[7];
  const float* ln1_g = (const float*)d_in[8];
  const float* ln1_b = (const float*)d_in[9];
  const float* ln2_g = (const float*)d_in[10];
  const float* ln2_b = (const float*)d_in[11];
  const float* ln3_g = (const float*)d_in[12];
  const float* ln3_b = (const float*)d_in[13];
  const float* vproj_w = (const float*)d_in[14];
  const float* vproj_b = (const float*)d_in[15];
  const float* off_w = (const float*)d_in[16];
  const float* off_b = (const float*)d_in[17];
  const float* aw_w = (const float*)d_in[18];
  const float* aw_b = (const float*)d_in[19];
  const float* oproj_w = (const float*)d_in[20];
  const float* oproj_b = (const float*)d_in[21];
  const float* lin1_w = (const float*)d_in[22];
  const float* lin1_b = (const float*)d_in[23];
  const float* lin2_w = (const float*)d_in[24];
  const float* lin2_b = (const float*)d_in[25];
  const unsigned char* mem_mask = (const unsigned char*)d_in[27];
  float* out = (float*)d_out;

  float* ws = (float*)d_ws;
  float* qp = ws + 0;
  float* qkbuf = ws + 921600;
  float* vbuf = ws + 2764800;
  float* sa = ws + 3686400;
  float* tmp = ws + 4608000;
  float* tgt2 = ws + 5529600;
  float* query = ws + 6451200;
  float* offb = ws + 7372800;
  float* awlin = ws + 8294400;
  float* accb = ws + 8755200;
  float* tgt3 = ws + 9676800;
  float* ff1 = ws + 10598400;
  short* valueBf = (short*)(ws + 14284800);  // 22282240 shorts
  short* wbase = valueBf + 22282240;
  short* inprojT = wbase + 0;        // [768][256]
  short* outprojT = wbase + 196608;  // [256][256]
  short* vprojT = wbase + 262144;    // [256][256]
  short* oprojT = wbase + 327680;    // [256][256]
  short* lin1T = wbase + 393216;     // [1024][256]
  short* lin2T = wbase + 655360;     // [256][1024]

  pack_w_k<<<192, 256, 0, stream>>>(in_proj_w, inprojT, 256, 768);
  pack_w_k<<<64, 256, 0, stream>>>(out_proj_w, outprojT, 256, 256);
  pack_w_k<<<64, 256, 0, stream>>>(vproj_w, vprojT, 256, 256);
  pack_w_k<<<64, 256, 0, stream>>>(oproj_w, oprojT, 256, 256);
  pack_w_k<<<256, 256, 0, stream>>>(lin1_w, lin1T, 256, 1024);
  pack_w_k<<<256, 256, 0, stream>>>(lin2_w, lin2T, 1024, 256);

  add_k<<<900, 256, 0, stream>>>(tgt, query_pos, qp);

  gemm_k<0, 0><<<57 * 8, 256, 0, stream>>>(qp, inprojT, in_proj_b, qkbuf, M1, 512, 256, nullptr);
  gemm_k<0, 0><<<57 * 4, 256, 0, stream>>>(tgt, inprojT + 512 * 256, in_proj_b + 512, vbuf, M1, 256, 256, nullptr);
  attn_k<<<Bc * Hc * NQT, 256, 0, stream>>>(qkbuf, vbuf, sa);

  gemm_k<0, 0><<<57 * 4, 256, 0, stream>>>(sa, outprojT, out_proj_b, tmp, M1, 256, 256, nullptr);
  ln_k<<<900, 256, 0, stream>>>(tgt, tmp, ln2_g, ln2_b, tgt2, query_pos, query);
  // value projection: bf16 MFMA (quantization to bf16 already proven benign)
  gemm_k<0, 1><<<1360 * 4, 256, 0, stream>>>(memory, vprojT, vproj_b, valueBf, Bc * Sc, 256, 256, mem_mask);
  // off/aw stay exact fp32: sampler-amplified precision path
  gemm32_k<0, 0><<<57 * 4, 256, 0, stream>>>(query, off_w, off_b, offb, M1, 256, 256, nullptr);
  gemm32_k<0, 0><<<57 * 2, 256, 0, stream>>>(query, aw_w, aw_b, awlin, M1, 128, 256, nullptr);
  sample_k<<<Bc * NQc * Hc / 4, 256, 0, stream>>>(awlin, offb, refp, valueBf, accb);
  gemm_k<0, 0><<<57 * 4, 256, 0, stream>>>(accb, oprojT, oproj_b, tmp, M1, 256, 256, nullptr);
  ln_k<<<900, 256, 0, stream>>>(tgt2, tmp, ln1_g, ln1_b, tgt3, nullptr, nullptr);
  gemm_k<1, 0><<<57 * 16, 256, 0, stream>>>(tgt3, lin1T, lin1_b, ff1, M1, 1024, 256, nullptr);
  gemm_k<0, 0><<<57 * 4, 256, 0, stream>>>(ff1, lin2T, lin2_b, tmp, M1, 256, 1024, nullptr);
  ln_k<<<900, 256, 0, stream>>>(tgt3, tmp, ln3_g, ln3_b, out, nullptr, nullptr);
}

// Round 4
// 493.661 us; speedup vs baseline: 1.3302x; 1.0032x over previous
//
#include <hip/hip_runtime.h>
#include <hip/hip_bf16.h>

typedef __attribute__((ext_vector_type(8))) short bf16x8;
typedef __attribute__((ext_vector_type(4))) short bf16x4;
typedef __attribute__((ext_vector_type(4))) float f32x4;

#define DEV static __device__ __forceinline__

constexpr int Bc = 4, NQc = 900, Hc = 8, Sc = 21760;
constexpr int M1 = Bc * NQc;           // 3600
constexpr int NQT = (NQc + 63) / 64;   // 15

DEV short f2bf(float f) {
  union { __hip_bfloat16 h; short s; } u;
  u.h = __float2bfloat16(f);
  return u.s;
}
DEV float bf2f(short s) {
  union { short s; __hip_bfloat16 h; } u;
  u.s = s;
  return __bfloat162float(u.h);
}

// ---------------------------------------------------------------------------
// All weight packs fused: W[K][N] f32 -> Wt[N][K] bf16, 6 segments.
DEV void pack_body(const float* W, short* Wt, int K, int N, int t) {
  int kq = K >> 2;
  int n = t / kq;
  int k4 = (t - n * kq) * 4;
  bf16x4 o;
  o[0] = f2bf(W[(size_t)(k4 + 0) * N + n]);
  o[1] = f2bf(W[(size_t)(k4 + 1) * N + n]);
  o[2] = f2bf(W[(size_t)(k4 + 2) * N + n]);
  o[3] = f2bf(W[(size_t)(k4 + 3) * N + n]);
  *(bf16x4*)&Wt[(size_t)n * K + k4] = o;
}

__global__ __launch_bounds__(256) void pack_all_k(
    const float* w0, short* t0,   // in_proj   K256 N768  -> 49152
    const float* w1, short* t1,   // out_proj  K256 N256  -> 16384
    const float* w2, short* t2,   // vproj     K256 N256  -> 16384
    const float* w3, short* t3,   // oproj     K256 N256  -> 16384
    const float* w4, short* t4,   // lin1      K256 N1024 -> 65536
    const float* w5, short* t5) { // lin2      K1024 N256 -> 65536
  int t = blockIdx.x * 256 + threadIdx.x;
  if (t < 49152) pack_body(w0, t0, 256, 768, t);
  else if (t < 65536) pack_body(w1, t1, 256, 256, t - 49152);
  else if (t < 81920) pack_body(w2, t2, 256, 256, t - 65536);
  else if (t < 98304) pack_body(w3, t3, 256, 256, t - 81920);
  else if (t < 163840) pack_body(w4, t4, 256, 1024, t - 98304);
  else pack_body(w5, t5, 1024, 256, t - 163840);
}

// ---------------------------------------------------------------------------
// Wide bf16 MFMA GEMM: 64M x 256N block tile, 4 waves (one per 64-col strip),
// K-step 64, 16 MFMA per 8 ds_read_b128 per wave per 32-K. A fp32 (+optional
// A2 added), Wt bf16 [N][K]. A fetched exactly once per element.
template <int ACT, int OUTBF16>
__global__ __launch_bounds__(256) void gemmw_k(
    const float* __restrict__ A, const float* __restrict__ A2,
    const short* __restrict__ Wt, const float* __restrict__ bias,
    void* __restrict__ Cv, int M, int N, int K,
    const unsigned char* __restrict__ rowmask) {
  __shared__ short As[64 * 72];
  __shared__ short Ws[256 * 72];
  const int nb = N >> 8;
  const int bm = blockIdx.x / nb, bn = blockIdx.x - bm * nb;
  const int tid = threadIdx.x;
  const int lane = tid & 63, wave = tid >> 6;
  const int l16 = lane & 15, quad = lane >> 4;

  f32x4 acc[4][4] = {};

  const int sr = tid >> 2, sk = (tid & 3) * 16;
  const int arow = bm * 64 + sr;
  const float* ap = A + (size_t)arow * K + sk;
  const float* ap2 = A2 ? A2 + (size_t)arow * K + sk : nullptr;
  const short* wp = Wt + (size_t)(bn * 256 + tid) * K;
  short* asd = &As[sr * 72 + sk];

  for (int k0 = 0; k0 < K; k0 += 64) {
    // stage A (fp32 -> bf16), 16 elements/thread
    {
      float4 v[4];
      if (arow < M) {
#pragma unroll
        for (int i = 0; i < 4; i++) v[i] = *(const float4*)(ap + k0 + i * 4);
        if (ap2) {
#pragma unroll
          for (int i = 0; i < 4; i++) {
            float4 w = *(const float4*)(ap2 + k0 + i * 4);
            v[i].x += w.x; v[i].y += w.y; v[i].z += w.z; v[i].w += w.w;
          }
        }
      } else {
#pragma unroll
        for (int i = 0; i < 4; i++) v[i] = make_float4(0.f, 0.f, 0.f, 0.f);
      }
      bf16x8 t0, t1;
      t0[0] = f2bf(v[0].x); t0[1] = f2bf(v[0].y); t0[2] = f2bf(v[0].z); t0[3] = f2bf(v[0].w);
      t0[4] = f2bf(v[1].x); t0[5] = f2bf(v[1].y); t0[6] = f2bf(v[1].z); t0[7] = f2bf(v[1].w);
      t1[0] = f2bf(v[2].x); t1[1] = f2bf(v[2].y); t1[2] = f2bf(v[2].z); t1[3] = f2bf(v[2].w);
      t1[4] = f2bf(v[3].x); t1[5] = f2bf(v[3].y); t1[6] = f2bf(v[3].z); t1[7] = f2bf(v[3].w);
      *(bf16x8*)asd = t0;
      *(bf16x8*)(asd + 8) = t1;
    }
    // stage W: each thread copies its n-row's 64-K slice (8 x b128)
    {
      const short* wq = wp + k0;
      short* wd = &Ws[tid * 72];
#pragma unroll
      for (int i = 0; i < 8; i++)
        *(bf16x8*)(wd + i * 8) = *(const bf16x8*)(wq + i * 8);
    }
    __syncthreads();
#pragma unroll
    for (int ks = 0; ks < 64; ks += 32) {
      bf16x8 af[4], bv[4];
#pragma unroll
      for (int i = 0; i < 4; i++)
        af[i] = *(const bf16x8*)&As[(i * 16 + l16) * 72 + quad * 8 + ks];
#pragma unroll
      for (int j = 0; j < 4; j++)
        bv[j] = *(const bf16x8*)&Ws[(wave * 64 + j * 16 + l16) * 72 + quad * 8 + ks];
#pragma unroll
      for (int i = 0; i < 4; i++)
#pragma unroll
        for (int j = 0; j < 4; j++)
          acc[i][j] = __builtin_amdgcn_mfma_f32_16x16x32_bf16(af[i], bv[j], acc[i][j], 0, 0, 0);
    }
    __syncthreads();
  }
#pragma unroll
  for (int i = 0; i < 4; i++) {
#pragma unroll
    for (int j = 0; j < 4; j++) {
      const int col = bn * 256 + wave * 64 + j * 16 + l16;
      const float bb = bias[col];
#pragma unroll
      for (int r = 0; r < 4; r++) {
        const int m = bm * 64 + i * 16 + quad * 4 + r;
        if (m < M) {
          float v = acc[i][j][r] + bb;
          if (ACT == 1) v = fmaxf(v, 0.f);
          if (rowmask && rowmask[m]) v = 0.f;
          if (OUTBF16)
            ((short*)Cv)[(size_t)m * N + col] = f2bf(v);
          else
            ((float*)Cv)[(size_t)m * N + col] = v;
        }
      }
    }
  }
}

// ---------------------------------------------------------------------------
// 64x64-tile bf16 MFMA GEMM (small-M, N=256 cases: v/out/oproj/lin2)
template <int ACT, int OUTBF16>
__global__ __launch_bounds__(256) void gemm_k(
    const float* __restrict__ A, const short* __restrict__ Wt,
    const float* __restrict__ bias, void* __restrict__ Cv, int M, int N, int K,
    const unsigned char* __restrict__ rowmask) {
  __shared__ short As[64 * 40];
  __shared__ short Ws[64 * 40];
  const int nb = N >> 6;
  const int bm = blockIdx.x / nb, bn = blockIdx.x % nb;
  const int tid = threadIdx.x;
  const int lane = tid & 63, wave = tid >> 6;
  const int wm = (wave >> 1) * 32, wn = (wave & 1) * 32;
  const int l16 = lane & 15, quad = lane >> 4;
  const int sr = tid >> 2, sk = (tid & 3) * 8;

  f32x4 acc[2][2] = {};
  const int arow = bm * 64 + sr;
  const float* ap = A + (size_t)arow * K + sk;
  const short* wp = Wt + (size_t)(bn * 64 + sr) * K + sk;
  short* asd = &As[sr * 40 + sk];
  short* wsd = &Ws[sr * 40 + sk];

  for (int k0 = 0; k0 < K; k0 += 32) {
    float4 v0, v1;
    if (arow < M) {
      v0 = *(const float4*)(ap + k0);
      v1 = *(const float4*)(ap + k0 + 4);
    } else {
      v0 = make_float4(0.f, 0.f, 0.f, 0.f);
      v1 = v0;
    }
    bf16x8 t;
    t[0] = f2bf(v0.x); t[1] = f2bf(v0.y); t[2] = f2bf(v0.z); t[3] = f2bf(v0.w);
    t[4] = f2bf(v1.x); t[5] = f2bf(v1.y); t[6] = f2bf(v1.z); t[7] = f2bf(v1.w);
    *(bf16x8*)asd = t;
    *(bf16x8*)wsd = *(const bf16x8*)(wp + k0);
    __syncthreads();
    bf16x8 a0 = *(const bf16x8*)&As[(wm + l16) * 40 + quad * 8];
    bf16x8 a1 = *(const bf16x8*)&As[(wm + 16 + l16) * 40 + quad * 8];
    bf16x8 b0 = *(const bf16x8*)&Ws[(wn + l16) * 40 + quad * 8];
    bf16x8 b1 = *(const bf16x8*)&Ws[(wn + 16 + l16) * 40 + quad * 8];
    acc[0][0] = __builtin_amdgcn_mfma_f32_16x16x32_bf16(a0, b0, acc[0][0], 0, 0, 0);
    acc[0][1] = __builtin_amdgcn_mfma_f32_16x16x32_bf16(a0, b1, acc[0][1], 0, 0, 0);
    acc[1][0] = __builtin_amdgcn_mfma_f32_16x16x32_bf16(a1, b0, acc[1][0], 0, 0, 0);
    acc[1][1] = __builtin_amdgcn_mfma_f32_16x16x32_bf16(a1, b1, acc[1][1], 0, 0, 0);
    __syncthreads();
  }
#pragma unroll
  for (int mi = 0; mi < 2; mi++) {
#pragma unroll
    for (int ni = 0; ni < 2; ni++) {
      const int col = bn * 64 + wn + ni * 16 + l16;
      const float bv = bias[col];
#pragma unroll
      for (int r = 0; r < 4; r++) {
        const int m = bm * 64 + wm + mi * 16 + quad * 4 + r;
        if (m < M) {
          float v = acc[mi][ni][r] + bv;
          if (ACT == 1) v = fmaxf(v, 0.f);
          if (rowmask && rowmask[m]) v = 0.f;
          if (OUTBF16)
            ((short*)Cv)[(size_t)m * N + col] = f2bf(v);
          else
            ((float*)Cv)[(size_t)m * N + col] = v;
        }
      }
    }
  }
}

// ---------------------------------------------------------------------------
// Exact fp32 GEMM (off/aw projections only — sampler-amplified precision path)
template <int ACT, int OUTBF16>
__global__ __launch_bounds__(256) void gemm32_k(
    const float* __restrict__ A, const float* __restrict__ W,
    const float* __restrict__ bias, void* __restrict__ Cv, int M, int N, int K,
    const unsigned char* __restrict__ rowmask) {
  __shared__ float As[16][64];
  __shared__ float Bs[16][68];
  const int nb = N >> 6;
  const int bm = blockIdx.x / nb, bn = blockIdx.x % nb;
  const int tid = threadIdx.x;
  const int tm = tid >> 4, tn = tid & 15;
  float acc[4][4] = {};

  for (int k0 = 0; k0 < K; k0 += 16) {
    {
      const int m = tid >> 2, kk = (tid & 3) * 4;
      const int row = bm * 64 + m;
      float4 v = (row < M) ? *(const float4*)(A + (size_t)row * K + k0 + kk)
                           : make_float4(0.f, 0.f, 0.f, 0.f);
      As[kk + 0][m] = v.x; As[kk + 1][m] = v.y;
      As[kk + 2][m] = v.z; As[kk + 3][m] = v.w;
    }
    {
      const int kk = tid >> 4, n = (tid & 15) * 4;
      float4 v = *(const float4*)(W + (size_t)(k0 + kk) * N + bn * 64 + n);
      *(float4*)&Bs[kk][n] = v;
    }
    __syncthreads();
#pragma unroll
    for (int kk = 0; kk < 16; kk++) {
      float a[4], b[4];
#pragma unroll
      for (int i = 0; i < 4; i++) a[i] = As[kk][tm * 4 + i];
#pragma unroll
      for (int j = 0; j < 4; j++) b[j] = Bs[kk][tn * 4 + j];
#pragma unroll
      for (int i = 0; i < 4; i++)
#pragma unroll
        for (int j = 0; j < 4; j++) acc[i][j] = fmaf(a[i], b[j], acc[i][j]);
    }
    __syncthreads();
  }
#pragma unroll
  for (int i = 0; i < 4; i++) {
    const int row = bm * 64 + tm * 4 + i;
    if (row >= M) continue;
    const bool masked = rowmask && rowmask[row];
#pragma unroll
    for (int j = 0; j < 4; j++) {
      const int col = bn * 64 + tn * 4 + j;
      float v = acc[i][j] + bias[col];
      if (ACT == 1) v = fmaxf(v, 0.f);
      if (masked) v = 0.f;
      if (OUTBF16)
        ((short*)Cv)[(size_t)row * N + col] = f2bf(v);
      else
        ((float*)Cv)[(size_t)row * N + col] = v;
    }
  }
}

// ---------------------------------------------------------------------------
__global__ __launch_bounds__(256) void attn_k(const float* __restrict__ qk,
                                              const float* __restrict__ vbuf,
                                              float* __restrict__ sa) {
  __shared__ short Vt[32 * 72];
  __shared__ short Pb[4][16 * 72];
  const int bid = blockIdx.x;
  const int qt = bid % NQT, bh = bid / NQT;
  const int b = bh >> 3, h = bh & 7;
  const int tid = threadIdx.x, lane = tid & 63, wave = tid >> 6;
  const int l16 = lane & 15, quad = lane >> 4;

  const int q_local = qt * 64 + wave * 16 + l16;
  const int qrow = b * NQc + min(q_local, NQc - 1);
  const float scale = 0.17677669529663687f;
  bf16x8 qf;
  {
    const float* qp = qk + (size_t)qrow * 512 + h * 32 + quad * 8;
    float4 v0 = *(const float4*)qp, v1 = *(const float4*)(qp + 4);
    qf[0] = f2bf(v0.x * scale); qf[1] = f2bf(v0.y * scale);
    qf[2] = f2bf(v0.z * scale); qf[3] = f2bf(v0.w * scale);
    qf[4] = f2bf(v1.x * scale); qf[5] = f2bf(v1.y * scale);
    qf[6] = f2bf(v1.z * scale); qf[7] = f2bf(v1.w * scale);
  }
  f32x4 o0 = {}, o1 = {};
  float mrun[4] = {-1e30f, -1e30f, -1e30f, -1e30f};
  float lrun[4] = {0.f, 0.f, 0.f, 0.f};

  for (int kt = 0; kt < NQT; kt++) {
    const int k0 = kt * 64;
    __syncthreads();
#pragma unroll
    for (int i = 0; i < 8; i++) {
      int kk = i * 8 + (tid >> 5);
      int ch = tid & 31;
      int key = k0 + kk;
      float v = (key < NQc) ? vbuf[(size_t)(b * NQc + key) * 256 + h * 32 + ch] : 0.f;
      Vt[ch * 72 + kk] = f2bf(v);
    }
    __syncthreads();

    f32x4 s[4];
#pragma unroll
    for (int st = 0; st < 4; st++) {
      const int key = k0 + st * 16 + l16;
      const int krow = b * NQc + min(key, NQc - 1);
      const float* kp = qk + (size_t)krow * 512 + 256 + h * 32 + quad * 8;
      float4 v0 = *(const float4*)kp, v1 = *(const float4*)(kp + 4);
      bf16x8 kf;
      kf[0] = f2bf(v0.x); kf[1] = f2bf(v0.y); kf[2] = f2bf(v0.z); kf[3] = f2bf(v0.w);
      kf[4] = f2bf(v1.x); kf[5] = f2bf(v1.y); kf[6] = f2bf(v1.z); kf[7] = f2bf(v1.w);
      f32x4 z = {};
      s[st] = __builtin_amdgcn_mfma_f32_16x16x32_bf16(qf, kf, z, 0, 0, 0);
      if (key >= NQc) { s[st][0] = -1e30f; s[st][1] = -1e30f; s[st][2] = -1e30f; s[st][3] = -1e30f; }
    }
    float mnew[4], alpha[4];
#pragma unroll
    for (int r = 0; r < 4; r++) {
      float mx = fmaxf(fmaxf(s[0][r], s[1][r]), fmaxf(s[2][r], s[3][r]));
#pragma unroll
      for (int d = 1; d < 16; d <<= 1) mx = fmaxf(mx, __shfl_xor(mx, d));
      mnew[r] = fmaxf(mrun[r], mx);
      alpha[r] = __expf(mrun[r] - mnew[r]);
      mrun[r] = mnew[r];
    }
    float tsum[4] = {0.f, 0.f, 0.f, 0.f};
#pragma unroll
    for (int st = 0; st < 4; st++) {
#pragma unroll
      for (int r = 0; r < 4; r++) {
        float p = __expf(s[st][r] - mnew[r]);
        s[st][r] = p;
        tsum[r] += p;
      }
    }
#pragma unroll
    for (int r = 0; r < 4; r++) {
      float t = tsum[r];
#pragma unroll
      for (int d = 1; d < 16; d <<= 1) t += __shfl_xor(t, d);
      lrun[r] = lrun[r] * alpha[r] + t;
      o0[r] *= alpha[r];
      o1[r] *= alpha[r];
    }
    short* pw = Pb[wave];
#pragma unroll
    for (int st = 0; st < 4; st++)
#pragma unroll
      for (int r = 0; r < 4; r++)
        pw[(quad * 4 + r) * 72 + st * 16 + l16] = f2bf(s[st][r]);
#pragma unroll
    for (int c = 0; c < 2; c++) {
      bf16x8 pf = *(const bf16x8*)&pw[l16 * 72 + c * 32 + quad * 8];
      bf16x8 vf0 = *(const bf16x8*)&Vt[l16 * 72 + c * 32 + quad * 8];
      bf16x8 vf1 = *(const bf16x8*)&Vt[(16 + l16) * 72 + c * 32 + quad * 8];
      o0 = __builtin_amdgcn_mfma_f32_16x16x32_bf16(pf, vf0, o0, 0, 0, 0);
      o1 = __builtin_amdgcn_mfma_f32_16x16x32_bf16(pf, vf1, o1, 0, 0, 0);
    }
  }
#pragma unroll
  for (int r = 0; r < 4; r++) {
    const int q = qt * 64 + wave * 16 + quad * 4 + r;
    if (q < NQc) {
      const float inv = 1.f / lrun[r];
      sa[(size_t)(b * NQc + q) * 256 + h * 32 + l16] = o0[r] * inv;
      sa[(size_t)(b * NQc + q) * 256 + h * 32 + 16 + l16] = o1[r] * inv;
    }
  }
}

// ---------------------------------------------------------------------------
__global__ __launch_bounds__(256) void ln_k(
    const float* __restrict__ resid, const float* __restrict__ x,
    const float* __restrict__ g, const float* __restrict__ bta,
    float* __restrict__ out, const float* __restrict__ qpos,
    float* __restrict__ out2) {
  const int row = blockIdx.x * 4 + (threadIdx.x >> 6);
  const int lane = threadIdx.x & 63;
  const size_t base = (size_t)row * 256 + lane * 4;
  float4 rv = *(const float4*)(resid + base);
  float4 xv = *(const float4*)(x + base);
  float4 v = make_float4(rv.x + xv.x, rv.y + xv.y, rv.z + xv.z, rv.w + xv.w);
  float sum = v.x + v.y + v.z + v.w;
#pragma unroll
  for (int d = 1; d < 64; d <<= 1) sum += __shfl_xor(sum, d);
  const float mean = sum * (1.f / 256.f);
  float a0 = v.x - mean, a1 = v.y - mean, a2 = v.z - mean, a3 = v.w - mean;
  float vs = a0 * a0 + a1 * a1 + a2 * a2 + a3 * a3;
#pragma unroll
  for (int d = 1; d < 64; d <<= 1) vs += __shfl_xor(vs, d);
  const float rstd = rsqrtf(vs * (1.f / 256.f) + 1e-5f);
  float4 gv = *(const float4*)(g + lane * 4);
  float4 bv = *(const float4*)(bta + lane * 4);
  float4 o = make_float4(a0 * rstd * gv.x + bv.x, a1 * rstd * gv.y + bv.y,
                         a2 * rstd * gv.z + bv.z, a3 * rstd * gv.w + bv.w);
  *(float4*)(out + base) = o;
  if (out2) {
    float4 qv = *(const float4*)(qpos + base);
    *(float4*)(out2 + base) = make_float4(o.x + qv.x, o.y + qv.y, o.z + qv.z, o.w + qv.w);
  }
}

// ---------------------------------------------------------------------------
__global__ __launch_bounds__(256) void sample_k(
    const float* __restrict__ awlin, const float* __restrict__ off,
    const float* __restrict__ refp, const short* __restrict__ value,
    float* __restrict__ accout) {
  const int wid = blockIdx.x * 4 + (threadIdx.x >> 6);
  const int lane = threadIdx.x & 63;
  const int bq = wid >> 3, h = wid & 7;
  const int b = bq / NQc;
  const int l16 = lane & 15;

  float wraw = awlin[(size_t)bq * 128 + h * 16 + l16];
  float mx = wraw;
#pragma unroll
  for (int d = 1; d < 16; d <<= 1) mx = fmaxf(mx, __shfl_xor(mx, d));
  float e = __expf(wraw - mx), ssum = e;
#pragma unroll
  for (int d = 1; d < 16; d <<= 1) ssum += __shfl_xor(ssum, d);
  const float wnorm = e / ssum;

  const int ch = lane & 31, sub = lane >> 5;
  float facc = 0.f;
#pragma unroll
  for (int it = 0; it < 8; it++) {
    const int pt = it * 2 + sub;
    const float w = __shfl(wnorm, pt);
    const int l = pt >> 2;
    const int W = 128 >> l;
    const int start = (l == 0) ? 0 : (l == 1) ? 16384 : (l == 2) ? 20480 : 21504;
    const float offx = off[(size_t)bq * 256 + h * 32 + pt * 2];
    const float offy = off[(size_t)bq * 256 + h * 32 + pt * 2 + 1];
    const float rx = refp[(size_t)bq * 8 + l * 2];
    const float ry = refp[(size_t)bq * 8 + l * 2 + 1];
    const float x = rx * (float)W + offx - 0.5f;
    const float y = ry * (float)W + offy - 0.5f;
    const float x0f = floorf(x), y0f = floorf(y);
    const float wx = x - x0f, wy = y - y0f;
    const int x0 = (int)x0f, y0 = (int)y0f;
    const short* vb = value + ((size_t)b * Sc + start) * 256 + h * 32 + ch;
#pragma unroll
    for (int c4 = 0; c4 < 4; c4++) {
      const int dx = c4 & 1, dy = c4 >> 1;
      const int xi = x0 + dx, yi = y0 + dy;
      const bool valid = (xi >= 0) && (xi < W) && (yi >= 0) && (yi < W);
      const int xc = min(max(xi, 0), W - 1);
      const int yc = min(max(yi, 0), W - 1);
      const float gvv = bf2f(vb[(size_t)(yc * W + xc) * 256]);
      const float ww = (dx ? wx : 1.f - wx) * (dy ? wy : 1.f - wy);
      facc += valid ? w * ww * gvv : 0.f;
    }
  }
  facc += __shfl_xor(facc, 32);
  if (lane < 32) accout[(size_t)bq * 256 + h * 32 + ch] = facc;
}

// ---------------------------------------------------------------------------
extern "C" void kernel_launch(void* const* d_in, const int* in_sizes, int n_in,
                              void* d_out, int out_size, void* d_ws,
                              size_t ws_size, hipStream_t stream) {
  const float* tgt = (const float*)d_in[0];
  const float* query_pos = (const float*)d_in[1];
  const float* refp = (const float*)d_in[2];
  const float* memory = (const float*)d_in[3];
  const float* in_proj_w = (const float*)d_in[4];
  const float* in_proj_b = (const float*)d_in[5];
  const float* out_proj_w = (const float*)d_in[6];
  const float* out_proj_b = (const float*)d_in[7];
  const float* ln1_g = (const float*)d_in[8];
  const float* ln1_b = (const float*)d_in[9];
  const float* ln2_g = (const float*)d_in[10];
  const float* ln2_b = (const float*)d_in[11];
  const float* ln3_g = (const float*)d_in[12];
  const float* ln3_b = (const float*)d_in[13];
  const float* vproj_w = (const float*)d_in[14];
  const float* vproj_b = (const float*)d_in[15];
  const float* off_w = (const float*)d_in[16];
  const float* off_b = (const float*)d_in[17];
  const float* aw_w = (const float*)d_in[18];
  const float* aw_b = (const float*)d_in[19];
  const float* oproj_w = (const float*)d_in[20];
  const float* oproj_b = (const float*)d_in[21];
  const float* lin1_w = (const float*)d_in[22];
  const float* lin1_b = (const float*)d_in[23];
  const float* lin2_w = (const float*)d_in[24];
  const float* lin2_b = (const float*)d_in[25];
  const unsigned char* mem_mask = (const unsigned char*)d_in[27];
  float* out = (float*)d_out;

  float* ws = (float*)d_ws;
  float* qkbuf = ws + 921600;
  float* vbuf = ws + 2764800;
  float* sa = ws + 3686400;
  float* tmp = ws + 4608000;
  float* tgt2 = ws + 5529600;
  float* query = ws + 6451200;
  float* offb = ws + 7372800;
  float* awlin = ws + 8294400;
  float* accb = ws + 8755200;
  float* tgt3 = ws + 9676800;
  float* ff1 = ws + 10598400;
  short* valueBf = (short*)(ws + 14284800);  // 22282240 shorts
  short* wbase = valueBf + 22282240;
  short* inprojT = wbase + 0;        // [768][256]
  short* outprojT = wbase + 196608;  // [256][256]
  short* vprojT = wbase + 262144;    // [256][256]
  short* oprojT = wbase + 327680;    // [256][256]
  short* lin1T = wbase + 393216;     // [1024][256]
  short* lin2T = wbase + 655360;     // [256][1024]

  pack_all_k<<<896, 256, 0, stream>>>(in_proj_w, inprojT, out_proj_w, outprojT,
                                      vproj_w, vprojT, oproj_w, oprojT,
                                      lin1_w, lin1T, lin2_w, lin2T);

  // q|k = (tgt + query_pos) @ in_proj[:, :512]   (add fused)
  gemmw_k<0, 0><<<57 * 2, 256, 0, stream>>>(tgt, query_pos, inprojT, in_proj_b, qkbuf, M1, 512, 256, nullptr);
  gemm_k<0, 0><<<57 * 4, 256, 0, stream>>>(tgt, inprojT + 512 * 256, in_proj_b + 512, vbuf, M1, 256, 256, nullptr);
  attn_k<<<Bc * Hc * NQT, 256, 0, stream>>>(qkbuf, vbuf, sa);

  gemm_k<0, 0><<<57 * 4, 256, 0, stream>>>(sa, outprojT, out_proj_b, tmp, M1, 256, 256, nullptr);
  ln_k<<<900, 256, 0, stream>>>(tgt, tmp, ln2_g, ln2_b, tgt2, query_pos, query);
  // value = memory @ vproj -> bf16, wide tile: A fetched once
  gemmw_k<0, 1><<<1360, 256, 0, stream>>>(memory, nullptr, vprojT, vproj_b, valueBf, Bc * Sc, 256, 256, mem_mask);
  // off/aw exact fp32 (sampler-amplified precision path)
  gemm32_k<0, 0><<<57 * 4, 256, 0, stream>>>(query, off_w, off_b, offb, M1, 256, 256, nullptr);
  gemm32_k<0, 0><<<57 * 2, 256, 0, stream>>>(query, aw_w, aw_b, awlin, M1, 128, 256, nullptr);
  sample_k<<<Bc * NQc * Hc / 4, 256, 0, stream>>>(awlin, offb, refp, valueBf, accb);
  gemm_k<0, 0><<<57 * 4, 256, 0, stream>>>(accb, oprojT, oproj_b, tmp, M1, 256, 256, nullptr);
  ln_k<<<900, 256, 0, stream>>>(tgt2, tmp, ln1_g, ln1_b, tgt3, nullptr, nullptr);
  gemmw_k<1, 0><<<57 * 4, 256, 0, stream>>>(tgt3, nullptr, lin1T, lin1_b, ff1, M1, 1024, 256, nullptr);
  gemm_k<0, 0><<<57 * 4, 256, 0, stream>>>(ff1, lin2T, lin2_b, tmp, M1, 256, 1024, nullptr);
  ln_k<<<900, 256, 0, stream>>>(tgt3, tmp, ln3_g, ln3_b, out, nullptr, nullptr);
}

// Round 5
// 487.136 us; speedup vs baseline: 1.3480x; 1.0134x over previous
//
#include <hip/hip_runtime.h>
#include <hip/hip_bf16.h>

typedef __attribute__((ext_vector_type(8))) short bf16x8;
typedef __attribute__((ext_vector_type(4))) short bf16x4;
typedef __attribute__((ext_vector_type(4))) float f32x4;

#define DEV static __device__ __forceinline__

constexpr int Bc = 4, NQc = 900, Hc = 8, Sc = 21760;
constexpr int M1 = Bc * NQc;           // 3600
constexpr int NQT = (NQc + 63) / 64;   // 15

DEV short f2bf(float f) {
  union { __hip_bfloat16 h; short s; } u;
  u.h = __float2bfloat16(f);
  return u.s;
}
DEV float bf2f(short s) {
  union { short s; __hip_bfloat16 h; } u;
  u.s = s;
  return __bfloat162float(u.h);
}

// ---------------------------------------------------------------------------
// Pack W[K][N] f32 -> k-tiled bf16 layout [K/32][N][32] (coalesced GEMM staging)
DEV void pack_body(const float* W, short* Wt, int K, int N, int t) {
  int kq = K >> 2;
  int n = t / kq;
  int k4 = (t - n * kq) * 4;
  bf16x4 o;
  o[0] = f2bf(W[(size_t)(k4 + 0) * N + n]);
  o[1] = f2bf(W[(size_t)(k4 + 1) * N + n]);
  o[2] = f2bf(W[(size_t)(k4 + 2) * N + n]);
  o[3] = f2bf(W[(size_t)(k4 + 3) * N + n]);
  *(bf16x4*)&Wt[((size_t)(k4 >> 5) * N + n) * 32 + (k4 & 31)] = o;
}

__global__ __launch_bounds__(256) void pack_all_k(
    const float* w0, short* t0,   // in_proj   K256 N768  -> 49152
    const float* w1, short* t1,   // out_proj  K256 N256  -> 16384
    const float* w2, short* t2,   // vproj     K256 N256  -> 16384
    const float* w3, short* t3,   // oproj     K256 N256  -> 16384
    const float* w4, short* t4,   // lin1      K256 N1024 -> 65536
    const float* w5, short* t5) { // lin2      K1024 N256 -> 65536
  int t = blockIdx.x * 256 + threadIdx.x;
  if (t < 49152) pack_body(w0, t0, 256, 768, t);
  else if (t < 65536) pack_body(w1, t1, 256, 256, t - 49152);
  else if (t < 81920) pack_body(w2, t2, 256, 256, t - 65536);
  else if (t < 98304) pack_body(w3, t3, 256, 256, t - 81920);
  else if (t < 163840) pack_body(w4, t4, 256, 1024, t - 98304);
  else pack_body(w5, t5, 1024, 256, t - 163840);
}

// ---------------------------------------------------------------------------
// Unified 64M x 256N bf16 MFMA GEMM, K-step 32, k-tiled weights, reg prefetch.
// MODE 0: f32 out (+ACT relu), col base bn*256
// MODE 1: bf16 out + rowmask (value proj)
// MODE 2: qkv fused: bn<2 -> (A+A2)@W -> Cv (stride 512, col bn*256); bn==2 ->
//         A@W -> C2 (stride 256)
// MODE 3: LN epilogue: Cv = LN(resid + A@W + bias)*g + beta;
//         optional out2 = Cv + qpos
template <int MODE, int ACT>
__global__ __launch_bounds__(256) void gemmv_k(
    const float* __restrict__ A, const float* __restrict__ A2,
    const short* __restrict__ Wt, const float* __restrict__ bias,
    void* __restrict__ Cv, float* __restrict__ C2, int M, int N, int K,
    const unsigned char* __restrict__ rowmask, const float* __restrict__ g,
    const float* __restrict__ beta, const float* __restrict__ resid,
    const float* __restrict__ qpos, float* __restrict__ out2) {
  __shared__ short As[64 * 40];
  __shared__ short Ws[256 * 40];
  const int nb = N >> 8;
  const int mb = blockIdx.x / nb, bn = blockIdx.x - mb * nb;
  const int tid = threadIdx.x;
  const int lane = tid & 63, wave = tid >> 6;
  const int l16 = lane & 15, quad = lane >> 4;
  const int sr = tid >> 2, sk = (tid & 3) * 8;
  const int arow = mb * 64 + sr;
  const bool aval = arow < M;
  const bool useA2 = (MODE == 2) ? (bn < 2) : (A2 != nullptr);
  const float* ap = A + (size_t)arow * K + sk;
  const float* ap2 = A2 ? A2 + (size_t)arow * K + sk : A;
  const short* wp = Wt + (size_t)(bn * 256 + tid) * 32;
  const size_t wstep = (size_t)N * 32;

  f32x4 acc[4][4] = {};
  float4 a0, a1;
  bf16x8 w0, w1, w2, w3;

  // prefetch iter 0
  if (aval) {
    a0 = *(const float4*)ap;
    a1 = *(const float4*)(ap + 4);
    if (useA2) {
      float4 b0 = *(const float4*)ap2, b1 = *(const float4*)(ap2 + 4);
      a0.x += b0.x; a0.y += b0.y; a0.z += b0.z; a0.w += b0.w;
      a1.x += b1.x; a1.y += b1.y; a1.z += b1.z; a1.w += b1.w;
    }
  } else {
    a0 = make_float4(0.f, 0.f, 0.f, 0.f);
    a1 = a0;
  }
  w0 = *(const bf16x8*)(wp + 0);
  w1 = *(const bf16x8*)(wp + 8);
  w2 = *(const bf16x8*)(wp + 16);
  w3 = *(const bf16x8*)(wp + 24);

  const int KT = K >> 5;
  for (int it = 0; it < KT; ++it) {
    {
      bf16x8 t;
      t[0] = f2bf(a0.x); t[1] = f2bf(a0.y); t[2] = f2bf(a0.z); t[3] = f2bf(a0.w);
      t[4] = f2bf(a1.x); t[5] = f2bf(a1.y); t[6] = f2bf(a1.z); t[7] = f2bf(a1.w);
      *(bf16x8*)&As[sr * 40 + sk] = t;
    }
    short* wd = &Ws[tid * 40];
    *(bf16x8*)(wd + 0) = w0;
    *(bf16x8*)(wd + 8) = w1;
    *(bf16x8*)(wd + 16) = w2;
    *(bf16x8*)(wd + 24) = w3;
    __syncthreads();
    if (it + 1 < KT) {
      const float* an = ap + (it + 1) * 32;
      if (aval) {
        a0 = *(const float4*)an;
        a1 = *(const float4*)(an + 4);
        if (useA2) {
          const float* an2 = ap2 + (it + 1) * 32;
          float4 b0 = *(const float4*)an2, b1 = *(const float4*)(an2 + 4);
          a0.x += b0.x; a0.y += b0.y; a0.z += b0.z; a0.w += b0.w;
          a1.x += b1.x; a1.y += b1.y; a1.z += b1.z; a1.w += b1.w;
        }
      }
      const short* wn = wp + (it + 1) * wstep;
      w0 = *(const bf16x8*)(wn + 0);
      w1 = *(const bf16x8*)(wn + 8);
      w2 = *(const bf16x8*)(wn + 16);
      w3 = *(const bf16x8*)(wn + 24);
    }
    bf16x8 af[4], bf[4];
#pragma unroll
    for (int i = 0; i < 4; i++)
      af[i] = *(const bf16x8*)&As[(i * 16 + l16) * 40 + quad * 8];
#pragma unroll
    for (int j = 0; j < 4; j++)
      bf[j] = *(const bf16x8*)&Ws[(wave * 64 + j * 16 + l16) * 40 + quad * 8];
#pragma unroll
    for (int i = 0; i < 4; i++)
#pragma unroll
      for (int j = 0; j < 4; j++)
        acc[i][j] = __builtin_amdgcn_mfma_f32_16x16x32_bf16(af[i], bf[j], acc[i][j], 0, 0, 0);
    __syncthreads();
  }

  // ---- epilogues ----
  if (MODE == 2) {
    const bool isqk = (bn < 2);
    float* dst = isqk ? (float*)Cv : C2;
    const int stride = isqk ? 512 : 256;
    const int cb = isqk ? bn * 256 : 0;
#pragma unroll
    for (int i = 0; i < 4; i++)
#pragma unroll
      for (int j = 0; j < 4; j++) {
        const int cl = wave * 64 + j * 16 + l16;
        const float bb = bias[bn * 256 + cl];
#pragma unroll
        for (int r = 0; r < 4; r++) {
          const int m = mb * 64 + i * 16 + quad * 4 + r;
          if (m < M) dst[(size_t)m * stride + cb + cl] = acc[i][j][r] + bb;
        }
      }
  } else if (MODE == 1) {
#pragma unroll
    for (int i = 0; i < 4; i++)
#pragma unroll
      for (int j = 0; j < 4; j++) {
        const int cl = wave * 64 + j * 16 + l16;
        const float bb = bias[cl];
#pragma unroll
        for (int r = 0; r < 4; r++) {
          const int m = mb * 64 + i * 16 + quad * 4 + r;
          if (m < M) {
            float v = acc[i][j][r] + bb;
            if (rowmask[m]) v = 0.f;
            ((short*)Cv)[(size_t)m * 256 + cl] = f2bf(v);
          }
        }
      }
  } else if (MODE == 0) {
#pragma unroll
    for (int i = 0; i < 4; i++)
#pragma unroll
      for (int j = 0; j < 4; j++) {
        const int cl = wave * 64 + j * 16 + l16;
        const int col = bn * 256 + cl;
        const float bb = bias[col];
#pragma unroll
        for (int r = 0; r < 4; r++) {
          const int m = mb * 64 + i * 16 + quad * 4 + r;
          if (m < M) {
            float v = acc[i][j][r] + bb;
            if (ACT == 1) v = fmaxf(v, 0.f);
            ((float*)Cv)[(size_t)m * N + col] = v;
          }
        }
      }
  } else {  // MODE 3: fused LayerNorm epilogue (N==256, bn==0)
    // v = acc + bias + resid (in place)
#pragma unroll
    for (int j = 0; j < 4; j++) {
      const int cl = wave * 64 + j * 16 + l16;
      const float bb = bias[cl];
#pragma unroll
      for (int i = 0; i < 4; i++)
#pragma unroll
        for (int r = 0; r < 4; r++) {
          const int m = mb * 64 + i * 16 + quad * 4 + r;
          const float rs = (m < M) ? resid[(size_t)m * 256 + cl] : 0.f;
          acc[i][j][r] += bb + rs;
        }
    }
    float2* pr = (float2*)As;  // [64 rows][4 waves], reuse LDS (post-barrier)
#pragma unroll
    for (int i = 0; i < 4; i++)
#pragma unroll
      for (int r = 0; r < 4; r++) {
        float s = 0.f, q = 0.f;
#pragma unroll
        for (int j = 0; j < 4; j++) {
          s += acc[i][j][r];
          q += acc[i][j][r] * acc[i][j][r];
        }
#pragma unroll
        for (int d = 1; d < 16; d <<= 1) {
          s += __shfl_xor(s, d);
          q += __shfl_xor(q, d);
        }
        if (l16 == 0) pr[(i * 16 + quad * 4 + r) * 4 + wave] = make_float2(s, q);
      }
    __syncthreads();
#pragma unroll
    for (int i = 0; i < 4; i++)
#pragma unroll
      for (int r = 0; r < 4; r++) {
        const int ml = i * 16 + quad * 4 + r;
        float2 p0 = pr[ml * 4 + 0], p1 = pr[ml * 4 + 1];
        float2 p2 = pr[ml * 4 + 2], p3 = pr[ml * 4 + 3];
        const float sum = p0.x + p1.x + p2.x + p3.x;
        const float sq = p0.y + p1.y + p2.y + p3.y;
        const float mean = sum * (1.f / 256.f);
        const float var = sq * (1.f / 256.f) - mean * mean;
        const float rstd = rsqrtf(var + 1e-5f);
        const int m = mb * 64 + ml;
        if (m < M) {
#pragma unroll
          for (int j = 0; j < 4; j++) {
            const int cl = wave * 64 + j * 16 + l16;
            const float o = (acc[i][j][r] - mean) * rstd * g[cl] + beta[cl];
            ((float*)Cv)[(size_t)m * 256 + cl] = o;
            if (out2) out2[(size_t)m * 256 + cl] = o + qpos[(size_t)m * 256 + cl];
          }
        }
      }
  }
}

// ---------------------------------------------------------------------------
// Exact fp32 GEMM body (off/aw: sampler-amplified precision path)
DEV void gemm32_body(const float* __restrict__ A, const float* __restrict__ W,
                     const float* __restrict__ bias, float* __restrict__ C,
                     int M, int N, int K, int bid) {
  __shared__ float Asf[16][64];
  __shared__ float Bsf[16][68];
  const int nb = N >> 6;
  const int bm = bid / nb, bn = bid % nb;
  const int tid = threadIdx.x;
  const int tm = tid >> 4, tn = tid & 15;
  float acc[4][4] = {};

  for (int k0 = 0; k0 < K; k0 += 16) {
    {
      const int m = tid >> 2, kk = (tid & 3) * 4;
      const int row = bm * 64 + m;
      float4 v = (row < M) ? *(const float4*)(A + (size_t)row * K + k0 + kk)
                           : make_float4(0.f, 0.f, 0.f, 0.f);
      Asf[kk + 0][m] = v.x; Asf[kk + 1][m] = v.y;
      Asf[kk + 2][m] = v.z; Asf[kk + 3][m] = v.w;
    }
    {
      const int kk = tid >> 4, n = (tid & 15) * 4;
      float4 v = *(const float4*)(W + (size_t)(k0 + kk) * N + bn * 64 + n);
      *(float4*)&Bsf[kk][n] = v;
    }
    __syncthreads();
#pragma unroll
    for (int kk = 0; kk < 16; kk++) {
      float a[4], b[4];
#pragma unroll
      for (int i = 0; i < 4; i++) a[i] = Asf[kk][tm * 4 + i];
#pragma unroll
      for (int j = 0; j < 4; j++) b[j] = Bsf[kk][tn * 4 + j];
#pragma unroll
      for (int i = 0; i < 4; i++)
#pragma unroll
        for (int j = 0; j < 4; j++) acc[i][j] = fmaf(a[i], b[j], acc[i][j]);
    }
    __syncthreads();
  }
#pragma unroll
  for (int i = 0; i < 4; i++) {
    const int row = bm * 64 + tm * 4 + i;
    if (row >= M) continue;
#pragma unroll
    for (int j = 0; j < 4; j++) {
      const int col = bn * 64 + tn * 4 + j;
      C[(size_t)row * N + col] = acc[i][j] + bias[col];
    }
  }
}

// off (228 blocks, N=256) + aw (114 blocks, N=128) in ONE launch
__global__ __launch_bounds__(256) void gemm32_offaw_k(
    const float* __restrict__ query, const float* __restrict__ off_w,
    const float* __restrict__ off_b, float* __restrict__ offb,
    const float* __restrict__ aw_w, const float* __restrict__ aw_b,
    float* __restrict__ awlin) {
  if (blockIdx.x < 228)
    gemm32_body(query, off_w, off_b, offb, M1, 256, 256, blockIdx.x);
  else
    gemm32_body(query, aw_w, aw_b, awlin, M1, 128, 256, blockIdx.x - 228);
}

// ---------------------------------------------------------------------------
__global__ __launch_bounds__(256) void attn_k(const float* __restrict__ qk,
                                              const float* __restrict__ vbuf,
                                              float* __restrict__ sa) {
  __shared__ short Vt[32 * 72];
  __shared__ short Pb[4][16 * 72];
  const int bid = blockIdx.x;
  const int qt = bid % NQT, bh = bid / NQT;
  const int b = bh >> 3, h = bh & 7;
  const int tid = threadIdx.x, lane = tid & 63, wave = tid >> 6;
  const int l16 = lane & 15, quad = lane >> 4;

  const int q_local = qt * 64 + wave * 16 + l16;
  const int qrow = b * NQc + min(q_local, NQc - 1);
  const float scale = 0.17677669529663687f;
  bf16x8 qf;
  {
    const float* qp = qk + (size_t)qrow * 512 + h * 32 + quad * 8;
    float4 v0 = *(const float4*)qp, v1 = *(const float4*)(qp + 4);
    qf[0] = f2bf(v0.x * scale); qf[1] = f2bf(v0.y * scale);
    qf[2] = f2bf(v0.z * scale); qf[3] = f2bf(v0.w * scale);
    qf[4] = f2bf(v1.x * scale); qf[5] = f2bf(v1.y * scale);
    qf[6] = f2bf(v1.z * scale); qf[7] = f2bf(v1.w * scale);
  }
  f32x4 o0 = {}, o1 = {};
  float mrun[4] = {-1e30f, -1e30f, -1e30f, -1e30f};
  float lrun[4] = {0.f, 0.f, 0.f, 0.f};

  for (int kt = 0; kt < NQT; kt++) {
    const int k0 = kt * 64;
    __syncthreads();
#pragma unroll
    for (int i = 0; i < 8; i++) {
      int kk = i * 8 + (tid >> 5);
      int ch = tid & 31;
      int key = k0 + kk;
      float v = (key < NQc) ? vbuf[(size_t)(b * NQc + key) * 256 + h * 32 + ch] : 0.f;
      Vt[ch * 72 + kk] = f2bf(v);
    }
    __syncthreads();

    f32x4 s[4];
#pragma unroll
    for (int st = 0; st < 4; st++) {
      const int key = k0 + st * 16 + l16;
      const int krow = b * NQc + min(key, NQc - 1);
      const float* kp = qk + (size_t)krow * 512 + 256 + h * 32 + quad * 8;
      float4 v0 = *(const float4*)kp, v1 = *(const float4*)(kp + 4);
      bf16x8 kf;
      kf[0] = f2bf(v0.x); kf[1] = f2bf(v0.y); kf[2] = f2bf(v0.z); kf[3] = f2bf(v0.w);
      kf[4] = f2bf(v1.x); kf[5] = f2bf(v1.y); kf[6] = f2bf(v1.z); kf[7] = f2bf(v1.w);
      f32x4 z = {};
      s[st] = __builtin_amdgcn_mfma_f32_16x16x32_bf16(qf, kf, z, 0, 0, 0);
      if (key >= NQc) { s[st][0] = -1e30f; s[st][1] = -1e30f; s[st][2] = -1e30f; s[st][3] = -1e30f; }
    }
    float mnew[4], alpha[4];
#pragma unroll
    for (int r = 0; r < 4; r++) {
      float mx = fmaxf(fmaxf(s[0][r], s[1][r]), fmaxf(s[2][r], s[3][r]));
#pragma unroll
      for (int d = 1; d < 16; d <<= 1) mx = fmaxf(mx, __shfl_xor(mx, d));
      mnew[r] = fmaxf(mrun[r], mx);
      alpha[r] = __expf(mrun[r] - mnew[r]);
      mrun[r] = mnew[r];
    }
    float tsum[4] = {0.f, 0.f, 0.f, 0.f};
#pragma unroll
    for (int st = 0; st < 4; st++) {
#pragma unroll
      for (int r = 0; r < 4; r++) {
        float p = __expf(s[st][r] - mnew[r]);
        s[st][r] = p;
        tsum[r] += p;
      }
    }
#pragma unroll
    for (int r = 0; r < 4; r++) {
      float t = tsum[r];
#pragma unroll
      for (int d = 1; d < 16; d <<= 1) t += __shfl_xor(t, d);
      lrun[r] = lrun[r] * alpha[r] + t;
      o0[r] *= alpha[r];
      o1[r] *= alpha[r];
    }
    short* pw = Pb[wave];
#pragma unroll
    for (int st = 0; st < 4; st++)
#pragma unroll
      for (int r = 0; r < 4; r++)
        pw[(quad * 4 + r) * 72 + st * 16 + l16] = f2bf(s[st][r]);
#pragma unroll
    for (int c = 0; c < 2; c++) {
      bf16x8 pf = *(const bf16x8*)&pw[l16 * 72 + c * 32 + quad * 8];
      bf16x8 vf0 = *(const bf16x8*)&Vt[l16 * 72 + c * 32 + quad * 8];
      bf16x8 vf1 = *(const bf16x8*)&Vt[(16 + l16) * 72 + c * 32 + quad * 8];
      o0 = __builtin_amdgcn_mfma_f32_16x16x32_bf16(pf, vf0, o0, 0, 0, 0);
      o1 = __builtin_amdgcn_mfma_f32_16x16x32_bf16(pf, vf1, o1, 0, 0, 0);
    }
  }
#pragma unroll
  for (int r = 0; r < 4; r++) {
    const int q = qt * 64 + wave * 16 + quad * 4 + r;
    if (q < NQc) {
      const float inv = 1.f / lrun[r];
      sa[(size_t)(b * NQc + q) * 256 + h * 32 + l16] = o0[r] * inv;
      sa[(size_t)(b * NQc + q) * 256 + h * 32 + 16 + l16] = o1[r] * inv;
    }
  }
}

// ---------------------------------------------------------------------------
__global__ __launch_bounds__(256) void sample_k(
    const float* __restrict__ awlin, const float* __restrict__ off,
    const float* __restrict__ refp, const short* __restrict__ value,
    float* __restrict__ accout) {
  const int wid = blockIdx.x * 4 + (threadIdx.x >> 6);
  const int lane = threadIdx.x & 63;
  const int bq = wid >> 3, h = wid & 7;
  const int b = bq / NQc;
  const int l16 = lane & 15;

  float wraw = awlin[(size_t)bq * 128 + h * 16 + l16];
  float mx = wraw;
#pragma unroll
  for (int d = 1; d < 16; d <<= 1) mx = fmaxf(mx, __shfl_xor(mx, d));
  float e = __expf(wraw - mx), ssum = e;
#pragma unroll
  for (int d = 1; d < 16; d <<= 1) ssum += __shfl_xor(ssum, d);
  const float wnorm = e / ssum;

  const int ch = lane & 31, sub = lane >> 5;
  float facc = 0.f;
#pragma unroll
  for (int it = 0; it < 8; it++) {
    const int pt = it * 2 + sub;
    const float w = __shfl(wnorm, pt);
    const int l = pt >> 2;
    const int W = 128 >> l;
    const int start = (l == 0) ? 0 : (l == 1) ? 16384 : (l == 2) ? 20480 : 21504;
    const float offx = off[(size_t)bq * 256 + h * 32 + pt * 2];
    const float offy = off[(size_t)bq * 256 + h * 32 + pt * 2 + 1];
    const float rx = refp[(size_t)bq * 8 + l * 2];
    const float ry = refp[(size_t)bq * 8 + l * 2 + 1];
    const float x = rx * (float)W + offx - 0.5f;
    const float y = ry * (float)W + offy - 0.5f;
    const float x0f = floorf(x), y0f = floorf(y);
    const float wx = x - x0f, wy = y - y0f;
    const int x0 = (int)x0f, y0 = (int)y0f;
    const short* vb = value + ((size_t)b * Sc + start) * 256 + h * 32 + ch;
#pragma unroll
    for (int c4 = 0; c4 < 4; c4++) {
      const int dx = c4 & 1, dy = c4 >> 1;
      const int xi = x0 + dx, yi = y0 + dy;
      const bool valid = (xi >= 0) && (xi < W) && (yi >= 0) && (yi < W);
      const int xc = min(max(xi, 0), W - 1);
      const int yc = min(max(yi, 0), W - 1);
      const float gvv = bf2f(vb[(size_t)(yc * W + xc) * 256]);
      const float ww = (dx ? wx : 1.f - wx) * (dy ? wy : 1.f - wy);
      facc += valid ? w * ww * gvv : 0.f;
    }
  }
  facc += __shfl_xor(facc, 32);
  if (lane < 32) accout[(size_t)bq * 256 + h * 32 + ch] = facc;
}

// ---------------------------------------------------------------------------
extern "C" void kernel_launch(void* const* d_in, const int* in_sizes, int n_in,
                              void* d_out, int out_size, void* d_ws,
                              size_t ws_size, hipStream_t stream) {
  const float* tgt = (const float*)d_in[0];
  const float* query_pos = (const float*)d_in[1];
  const float* refp = (const float*)d_in[2];
  const float* memory = (const float*)d_in[3];
  const float* in_proj_w = (const float*)d_in[4];
  const float* in_proj_b = (const float*)d_in[5];
  const float* out_proj_w = (const float*)d_in[6];
  const float* out_proj_b = (const float*)d_in[7];
  const float* ln1_g = (const float*)d_in[8];
  const float* ln1_b = (const float*)d_in[9];
  const float* ln2_g = (const float*)d_in[10];
  const float* ln2_b = (const float*)d_in[11];
  const float* ln3_g = (const float*)d_in[12];
  const float* ln3_b = (const float*)d_in[13];
  const float* vproj_w = (const float*)d_in[14];
  const float* vproj_b = (const float*)d_in[15];
  const float* off_w = (const float*)d_in[16];
  const float* off_b = (const float*)d_in[17];
  const float* aw_w = (const float*)d_in[18];
  const float* aw_b = (const float*)d_in[19];
  const float* oproj_w = (const float*)d_in[20];
  const float* oproj_b = (const float*)d_in[21];
  const float* lin1_w = (const float*)d_in[22];
  const float* lin1_b = (const float*)d_in[23];
  const float* lin2_w = (const float*)d_in[24];
  const float* lin2_b = (const float*)d_in[25];
  const unsigned char* mem_mask = (const unsigned char*)d_in[27];
  float* out = (float*)d_out;

  float* ws = (float*)d_ws;
  float* qkbuf = ws + 921600;     // [3600][512]
  float* vbuf = ws + 2764800;     // [3600][256]
  float* sa = ws + 3686400;
  float* tgt2 = ws + 5529600;
  float* query = ws + 6451200;
  float* offb = ws + 7372800;
  float* awlin = ws + 8294400;
  float* accb = ws + 8755200;
  float* tgt3 = ws + 9676800;
  float* ff1 = ws + 10598400;     // [3600][1024]
  short* valueBf = (short*)(ws + 14284800);  // 22282240 shorts
  short* wbase = valueBf + 22282240;
  short* inT = wbase + 0;         // tiled [8][768][32]
  short* outT = wbase + 196608;   // tiled [8][256][32]
  short* vT = wbase + 262144;
  short* oT = wbase + 327680;
  short* lin1T = wbase + 393216;  // tiled [8][1024][32]
  short* lin2T = wbase + 655360;  // tiled [32][256][32]

  pack_all_k<<<896, 256, 0, stream>>>(in_proj_w, inT, out_proj_w, outT,
                                      vproj_w, vT, oproj_w, oT,
                                      lin1_w, lin1T, lin2_w, lin2T);

  // fused q|k|v projection (q,k add query_pos; v plain tgt)
  gemmv_k<2, 0><<<57 * 3, 256, 0, stream>>>(
      tgt, query_pos, inT, in_proj_b, qkbuf, vbuf, M1, 768, 256,
      nullptr, nullptr, nullptr, nullptr, nullptr, nullptr);
  attn_k<<<Bc * Hc * NQT, 256, 0, stream>>>(qkbuf, vbuf, sa);
  // out_proj + residual + LN2, and query = tgt2 + query_pos
  gemmv_k<3, 0><<<57, 256, 0, stream>>>(
      sa, nullptr, outT, out_proj_b, tgt2, nullptr, M1, 256, 256,
      nullptr, ln2_g, ln2_b, tgt, query_pos, query);
  // value = memory @ vproj -> bf16 (masked rows zeroed)
  gemmv_k<1, 0><<<1360, 256, 0, stream>>>(
      memory, nullptr, vT, vproj_b, valueBf, nullptr, Bc * Sc, 256, 256,
      mem_mask, nullptr, nullptr, nullptr, nullptr, nullptr);
  // off + aw in one launch (exact fp32: sampler-amplified path)
  gemm32_offaw_k<<<342, 256, 0, stream>>>(query, off_w, off_b, offb, aw_w, aw_b, awlin);
  sample_k<<<Bc * NQc * Hc / 4, 256, 0, stream>>>(awlin, offb, refp, valueBf, accb);
  // oproj + residual + LN1
  gemmv_k<3, 0><<<57, 256, 0, stream>>>(
      accb, nullptr, oT, oproj_b, tgt3, nullptr, M1, 256, 256,
      nullptr, ln1_g, ln1_b, tgt2, nullptr, nullptr);
  // FFN
  gemmv_k<0, 1><<<57 * 4, 256, 0, stream>>>(
      tgt3, nullptr, lin1T, lin1_b, ff1, nullptr, M1, 1024, 256,
      nullptr, nullptr, nullptr, nullptr, nullptr, nullptr);
  gemmv_k<3, 0><<<57, 256, 0, stream>>>(
      ff1, nullptr, lin2T, lin2_b, out, nullptr, M1, 256, 1024,
      nullptr, ln3_g, ln3_b, tgt3, nullptr, nullptr);
}

// Round 6
// 470.350 us; speedup vs baseline: 1.3961x; 1.0357x over previous
//
#include <hip/hip_runtime.h>
#include <hip/hip_bf16.h>

typedef __attribute__((ext_vector_type(8))) short bf16x8;
typedef __attribute__((ext_vector_type(4))) short bf16x4;
typedef __attribute__((ext_vector_type(4))) float f32x4;

#define DEV static __device__ __forceinline__

constexpr int Bc = 4, NQc = 900, Hc = 8, Sc = 21760;
constexpr int M1 = Bc * NQc;           // 3600
constexpr int NQT = (NQc + 63) / 64;   // 15 key tiles of 64
constexpr int QT16 = (NQc + 15) / 16;  // 57 query tiles of 16

DEV short f2bf(float f) {
  union { __hip_bfloat16 h; short s; } u;
  u.h = __float2bfloat16(f);
  return u.s;
}
DEV float bf2f(short s) {
  union { short s; __hip_bfloat16 h; } u;
  u.s = s;
  return __bfloat162float(u.h);
}

// ---------------------------------------------------------------------------
// Pack W[K][N] f32 -> k-tiled bf16 [K/32][N][32]. Reads coalesced (lane = n),
// writes scattered (stores don't stall the pipe).
DEV void pack_body(const float* W, short* Wt, int K, int N, int t) {
  int n = t % N;
  int k4 = (t / N) * 4;
  bf16x4 o;
  o[0] = f2bf(W[(size_t)(k4 + 0) * N + n]);
  o[1] = f2bf(W[(size_t)(k4 + 1) * N + n]);
  o[2] = f2bf(W[(size_t)(k4 + 2) * N + n]);
  o[3] = f2bf(W[(size_t)(k4 + 3) * N + n]);
  *(bf16x4*)&Wt[((size_t)(k4 >> 5) * N + n) * 32 + (k4 & 31)] = o;
}

__global__ __launch_bounds__(256) void pack_all_k(
    const float* w0, short* t0, const float* w1, short* t1,
    const float* w2, short* t2, const float* w3, short* t3,
    const float* w4, short* t4, const float* w5, short* t5) {
  int t = blockIdx.x * 256 + threadIdx.x;
  if (t < 49152) pack_body(w0, t0, 256, 768, t);
  else if (t < 65536) pack_body(w1, t1, 256, 256, t - 49152);
  else if (t < 81920) pack_body(w2, t2, 256, 256, t - 65536);
  else if (t < 98304) pack_body(w3, t3, 256, 256, t - 81920);
  else if (t < 163840) pack_body(w4, t4, 256, 1024, t - 98304);
  else pack_body(w5, t5, 1024, 256, t - 163840);
}

// ---------------------------------------------------------------------------
// Unified MT x 256N bf16 MFMA GEMM, K-step 32, distance-2 register prefetch.
// MODE 0: f32 out (+ACT relu), col base bn*256
// MODE 1: bf16 out + rowmask (value proj)
// MODE 2: qkv fused (bn<2 -> q|k with A+A2, stride 512; bn==2 -> v, stride 256)
// MODE 3: LN epilogue (N=256): Cv = LN(resid + A@W + b)*g + beta [+ out2=+qpos]
template <int MODE, int ACT, int MT>
__global__ __launch_bounds__(256) void gemmv_k(
    const float* __restrict__ A, const float* __restrict__ A2,
    const short* __restrict__ Wt, const float* __restrict__ bias,
    void* __restrict__ Cv, float* __restrict__ C2, int M, int N, int K,
    const unsigned char* __restrict__ rowmask, const float* __restrict__ g,
    const float* __restrict__ beta, const float* __restrict__ resid,
    const float* __restrict__ qpos, float* __restrict__ out2) {
  constexpr int IT = MT / 16;
  __shared__ short As[MT * 40];
  __shared__ short Ws[256 * 40];
  const int nb = N >> 8;
  const int mb = blockIdx.x / nb, bn = blockIdx.x - mb * nb;
  const int tid = threadIdx.x;
  const int lane = tid & 63, wave = tid >> 6;
  const int l16 = lane & 15, quad = lane >> 4;
  const int sr = (MT == 64) ? (tid >> 2) : (tid >> 3);
  const int sk = (MT == 64) ? ((tid & 3) * 8) : ((tid & 7) * 4);
  const int arow = mb * MT + sr;
  const bool aval = arow < M;
  const bool useA2 = (MODE == 2) ? (bn < 2) : (A2 != nullptr);
  const float* ap = A + (size_t)arow * K + sk;
  const float* ap2 = (A2 ? A2 : A) + (size_t)arow * K + sk;
  const short* wp = Wt + (size_t)(bn * 256 + tid) * 32;
  const size_t wstep = (size_t)N * 32;
  const int KT = K >> 5;

  f32x4 acc[IT][4] = {};
  float4 pa0[2] = {}, pa1[2] = {};
  bf16x8 pw[2][4];

  auto loadA = [&](int s, int it) {
    if (aval) {
      const float* p = ap + it * 32;
      pa0[s] = *(const float4*)p;
      if constexpr (MT == 64) pa1[s] = *(const float4*)(p + 4);
      if (useA2) {
        const float* p2 = ap2 + it * 32;
        float4 q0 = *(const float4*)p2;
        pa0[s].x += q0.x; pa0[s].y += q0.y; pa0[s].z += q0.z; pa0[s].w += q0.w;
        if constexpr (MT == 64) {
          float4 q1 = *(const float4*)(p2 + 4);
          pa1[s].x += q1.x; pa1[s].y += q1.y; pa1[s].z += q1.z; pa1[s].w += q1.w;
        }
      }
    }
  };
  auto loadW = [&](int s, int it) {
    const short* p = wp + (size_t)it * wstep;
    pw[s][0] = *(const bf16x8*)(p + 0);
    pw[s][1] = *(const bf16x8*)(p + 8);
    pw[s][2] = *(const bf16x8*)(p + 16);
    pw[s][3] = *(const bf16x8*)(p + 24);
  };
  auto stage = [&](int s) {
    if constexpr (MT == 64) {
      bf16x8 t;
      t[0] = f2bf(pa0[s].x); t[1] = f2bf(pa0[s].y); t[2] = f2bf(pa0[s].z); t[3] = f2bf(pa0[s].w);
      t[4] = f2bf(pa1[s].x); t[5] = f2bf(pa1[s].y); t[6] = f2bf(pa1[s].z); t[7] = f2bf(pa1[s].w);
      *(bf16x8*)&As[sr * 40 + sk] = t;
    } else {
      bf16x4 t;
      t[0] = f2bf(pa0[s].x); t[1] = f2bf(pa0[s].y); t[2] = f2bf(pa0[s].z); t[3] = f2bf(pa0[s].w);
      *(bf16x4*)&As[sr * 40 + sk] = t;
    }
    short* wd = &Ws[tid * 40];
    *(bf16x8*)(wd + 0) = pw[s][0];
    *(bf16x8*)(wd + 8) = pw[s][1];
    *(bf16x8*)(wd + 16) = pw[s][2];
    *(bf16x8*)(wd + 24) = pw[s][3];
  };
  auto compute = [&]() {
    bf16x8 af[IT], bfr[4];
#pragma unroll
    for (int i = 0; i < IT; i++)
      af[i] = *(const bf16x8*)&As[(i * 16 + l16) * 40 + quad * 8];
#pragma unroll
    for (int j = 0; j < 4; j++)
      bfr[j] = *(const bf16x8*)&Ws[(wave * 64 + j * 16 + l16) * 40 + quad * 8];
#pragma unroll
    for (int i = 0; i < IT; i++)
#pragma unroll
      for (int j = 0; j < 4; j++)
        acc[i][j] = __builtin_amdgcn_mfma_f32_16x16x32_bf16(af[i], bfr[j], acc[i][j], 0, 0, 0);
  };

  loadA(0, 0); loadW(0, 0);
  loadA(1, 1); loadW(1, 1);
  for (int it = 0; it < KT; it += 2) {
    stage(0);
    __syncthreads();
    if (it + 2 < KT) { loadA(0, it + 2); loadW(0, it + 2); }
    compute();
    __syncthreads();
    stage(1);
    __syncthreads();
    if (it + 3 < KT) { loadA(1, it + 3); loadW(1, it + 3); }
    compute();
    __syncthreads();
  }

  // ---- epilogues ----
  if constexpr (MODE == 2) {
    const bool isqk = (bn < 2);
    float* dst = isqk ? (float*)Cv : C2;
    const int stride = isqk ? 512 : 256;
    const int cb = isqk ? bn * 256 : 0;
#pragma unroll
    for (int i = 0; i < IT; i++)
#pragma unroll
      for (int j = 0; j < 4; j++) {
        const int cl = wave * 64 + j * 16 + l16;
        const float bb = bias[bn * 256 + cl];
#pragma unroll
        for (int r = 0; r < 4; r++) {
          const int m = mb * MT + i * 16 + quad * 4 + r;
          if (m < M) dst[(size_t)m * stride + cb + cl] = acc[i][j][r] + bb;
        }
      }
  } else if constexpr (MODE == 1) {
#pragma unroll
    for (int i = 0; i < IT; i++)
#pragma unroll
      for (int j = 0; j < 4; j++) {
        const int cl = wave * 64 + j * 16 + l16;
        const float bb = bias[cl];
#pragma unroll
        for (int r = 0; r < 4; r++) {
          const int m = mb * MT + i * 16 + quad * 4 + r;
          if (m < M) {
            float v = acc[i][j][r] + bb;
            if (rowmask[m]) v = 0.f;
            ((short*)Cv)[(size_t)m * 256 + cl] = f2bf(v);
          }
        }
      }
  } else if constexpr (MODE == 0) {
#pragma unroll
    for (int i = 0; i < IT; i++)
#pragma unroll
      for (int j = 0; j < 4; j++) {
        const int cl = wave * 64 + j * 16 + l16;
        const int col = bn * 256 + cl;
        const float bb = bias[col];
#pragma unroll
        for (int r = 0; r < 4; r++) {
          const int m = mb * MT + i * 16 + quad * 4 + r;
          if (m < M) {
            float v = acc[i][j][r] + bb;
            if (ACT == 1) v = fmaxf(v, 0.f);
            ((float*)Cv)[(size_t)m * N + col] = v;
          }
        }
      }
  } else {  // MODE 3: fused LayerNorm epilogue (N==256)
#pragma unroll
    for (int j = 0; j < 4; j++) {
      const int cl = wave * 64 + j * 16 + l16;
      const float bb = bias[cl];
#pragma unroll
      for (int i = 0; i < IT; i++)
#pragma unroll
        for (int r = 0; r < 4; r++) {
          const int m = mb * MT + i * 16 + quad * 4 + r;
          const float rs = (m < M) ? resid[(size_t)m * 256 + cl] : 0.f;
          acc[i][j][r] += bb + rs;
        }
    }
    float2* pr = (float2*)As;  // [MT rows][4 waves], reuse LDS post-barrier
#pragma unroll
    for (int i = 0; i < IT; i++)
#pragma unroll
      for (int r = 0; r < 4; r++) {
        float s = 0.f, q = 0.f;
#pragma unroll
        for (int j = 0; j < 4; j++) {
          s += acc[i][j][r];
          q += acc[i][j][r] * acc[i][j][r];
        }
#pragma unroll
        for (int d = 1; d < 16; d <<= 1) {
          s += __shfl_xor(s, d);
          q += __shfl_xor(q, d);
        }
        if (l16 == 0) pr[(i * 16 + quad * 4 + r) * 4 + wave] = make_float2(s, q);
      }
    __syncthreads();
#pragma unroll
    for (int i = 0; i < IT; i++)
#pragma unroll
      for (int r = 0; r < 4; r++) {
        const int ml = i * 16 + quad * 4 + r;
        float2 p0 = pr[ml * 4 + 0], p1 = pr[ml * 4 + 1];
        float2 p2 = pr[ml * 4 + 2], p3 = pr[ml * 4 + 3];
        const float sum = p0.x + p1.x + p2.x + p3.x;
        const float sq = p0.y + p1.y + p2.y + p3.y;
        const float mean = sum * (1.f / 256.f);
        const float var = sq * (1.f / 256.f) - mean * mean;
        const float rstd = rsqrtf(var + 1e-5f);
        const int m = mb * MT + ml;
        if (m < M) {
#pragma unroll
          for (int j = 0; j < 4; j++) {
            const int cl = wave * 64 + j * 16 + l16;
            const float o = (acc[i][j][r] - mean) * rstd * g[cl] + beta[cl];
            ((float*)Cv)[(size_t)m * 256 + cl] = o;
            if (out2) out2[(size_t)m * 256 + cl] = o + qpos[(size_t)m * 256 + cl];
          }
        }
      }
  }
}

// ---------------------------------------------------------------------------
// Exact fp32 GEMM body (off/aw: sampler-amplified precision path)
DEV void gemm32_body(const float* __restrict__ A, const float* __restrict__ W,
                     const float* __restrict__ bias, float* __restrict__ C,
                     int M, int N, int K, int bid) {
  __shared__ float Asf[16][64];
  __shared__ float Bsf[16][68];
  const int nb = N >> 6;
  const int bm = bid / nb, bn = bid % nb;
  const int tid = threadIdx.x;
  const int tm = tid >> 4, tn = tid & 15;
  float acc[4][4] = {};

  for (int k0 = 0; k0 < K; k0 += 16) {
    {
      const int m = tid >> 2, kk = (tid & 3) * 4;
      const int row = bm * 64 + m;
      float4 v = (row < M) ? *(const float4*)(A + (size_t)row * K + k0 + kk)
                           : make_float4(0.f, 0.f, 0.f, 0.f);
      Asf[kk + 0][m] = v.x; Asf[kk + 1][m] = v.y;
      Asf[kk + 2][m] = v.z; Asf[kk + 3][m] = v.w;
    }
    {
      const int kk = tid >> 4, n = (tid & 15) * 4;
      float4 v = *(const float4*)(W + (size_t)(k0 + kk) * N + bn * 64 + n);
      *(float4*)&Bsf[kk][n] = v;
    }
    __syncthreads();
#pragma unroll
    for (int kk = 0; kk < 16; kk++) {
      float a[4], b[4];
#pragma unroll
      for (int i = 0; i < 4; i++) a[i] = Asf[kk][tm * 4 + i];
#pragma unroll
      for (int j = 0; j < 4; j++) b[j] = Bsf[kk][tn * 4 + j];
#pragma unroll
      for (int i = 0; i < 4; i++)
#pragma unroll
        for (int j = 0; j < 4; j++) acc[i][j] = fmaf(a[i], b[j], acc[i][j]);
    }
    __syncthreads();
  }
#pragma unroll
  for (int i = 0; i < 4; i++) {
    const int row = bm * 64 + tm * 4 + i;
    if (row >= M) continue;
#pragma unroll
    for (int j = 0; j < 4; j++) {
      const int col = bn * 64 + tn * 4 + j;
      C[(size_t)row * N + col] = acc[i][j] + bias[col];
    }
  }
}

__global__ __launch_bounds__(256) void gemm32_offaw_k(
    const float* __restrict__ query, const float* __restrict__ off_w,
    const float* __restrict__ off_b, float* __restrict__ offb,
    const float* __restrict__ aw_w, const float* __restrict__ aw_b,
    float* __restrict__ awlin) {
  if (blockIdx.x < 228)
    gemm32_body(query, off_w, off_b, offb, M1, 256, 256, blockIdx.x);
  else
    gemm32_body(query, aw_w, aw_b, awlin, M1, 128, 256, blockIdx.x - 228);
}

// ---------------------------------------------------------------------------
// Key-split flash attention. Block = (b, h, 16 queries); 4 waves each process
// key tiles kt = wave, wave+4, ... with NO barrier in the main loop (per-wave
// private LDS). One barrier, then (m,l,o) merge across waves.
__global__ __launch_bounds__(256) void attn_k(const float* __restrict__ qk,
                                              const float* __restrict__ vbuf,
                                              float* __restrict__ sa) {
  __shared__ short Vt[4][32 * 72];   // per-wave V^T tile [ch][key]
  __shared__ short Pb[4][16 * 72];   // per-wave P
  __shared__ float Om[4][16][32];    // partial O
  __shared__ float Ml[4][16][2];     // partial (m, l)
  const int bid = blockIdx.x;
  const int qt = bid % QT16, bh = bid / QT16;
  const int b = bh >> 3, h = bh & 7;
  const int tid = threadIdx.x, lane = tid & 63, wave = tid >> 6;
  const int l16 = lane & 15, quad = lane >> 4;

  const int q_local = qt * 16 + l16;
  const int qrow = b * NQc + min(q_local, NQc - 1);
  const float scale = 0.17677669529663687f;
  bf16x8 qf;
  {
    const float* qp = qk + (size_t)qrow * 512 + h * 32 + quad * 8;
    float4 v0 = *(const float4*)qp, v1 = *(const float4*)(qp + 4);
    qf[0] = f2bf(v0.x * scale); qf[1] = f2bf(v0.y * scale);
    qf[2] = f2bf(v0.z * scale); qf[3] = f2bf(v0.w * scale);
    qf[4] = f2bf(v1.x * scale); qf[5] = f2bf(v1.y * scale);
    qf[6] = f2bf(v1.z * scale); qf[7] = f2bf(v1.w * scale);
  }
  f32x4 o0 = {}, o1 = {};
  float mrun[4] = {-1e30f, -1e30f, -1e30f, -1e30f};
  float lrun[4] = {0.f, 0.f, 0.f, 0.f};

  short* vt = Vt[wave];
  short* pw = Pb[wave];
  const int vch = lane & 31, vkk = lane >> 5;

  for (int kt = wave; kt < NQT; kt += 4) {
    const int k0 = kt * 64;
    // stage V^T (per-wave, coalesced 2-key reads, no barrier needed)
#pragma unroll
    for (int i = 0; i < 32; i++) {
      const int key = k0 + 2 * i + vkk;
      const float v = (key < NQc) ? vbuf[(size_t)(b * NQc + key) * 256 + h * 32 + vch] : 0.f;
      vt[vch * 72 + 2 * i + vkk] = f2bf(v);
    }
    // QK^T
    f32x4 s[4];
#pragma unroll
    for (int st = 0; st < 4; st++) {
      const int key = k0 + st * 16 + l16;
      const int krow = b * NQc + min(key, NQc - 1);
      const float* kp = qk + (size_t)krow * 512 + 256 + h * 32 + quad * 8;
      float4 v0 = *(const float4*)kp, v1 = *(const float4*)(kp + 4);
      bf16x8 kf;
      kf[0] = f2bf(v0.x); kf[1] = f2bf(v0.y); kf[2] = f2bf(v0.z); kf[3] = f2bf(v0.w);
      kf[4] = f2bf(v1.x); kf[5] = f2bf(v1.y); kf[6] = f2bf(v1.z); kf[7] = f2bf(v1.w);
      f32x4 z = {};
      s[st] = __builtin_amdgcn_mfma_f32_16x16x32_bf16(qf, kf, z, 0, 0, 0);
      if (key >= NQc) { s[st][0] = -1e30f; s[st][1] = -1e30f; s[st][2] = -1e30f; s[st][3] = -1e30f; }
    }
    // online softmax
    float mnew[4], alpha[4];
#pragma unroll
    for (int r = 0; r < 4; r++) {
      float mx = fmaxf(fmaxf(s[0][r], s[1][r]), fmaxf(s[2][r], s[3][r]));
#pragma unroll
      for (int d = 1; d < 16; d <<= 1) mx = fmaxf(mx, __shfl_xor(mx, d));
      mnew[r] = fmaxf(mrun[r], mx);
      alpha[r] = __expf(mrun[r] - mnew[r]);
      mrun[r] = mnew[r];
    }
    float tsum[4] = {0.f, 0.f, 0.f, 0.f};
#pragma unroll
    for (int st = 0; st < 4; st++)
#pragma unroll
      for (int r = 0; r < 4; r++) {
        float p = __expf(s[st][r] - mnew[r]);
        s[st][r] = p;
        tsum[r] += p;
      }
#pragma unroll
    for (int r = 0; r < 4; r++) {
      float t = tsum[r];
#pragma unroll
      for (int d = 1; d < 16; d <<= 1) t += __shfl_xor(t, d);
      lrun[r] = lrun[r] * alpha[r] + t;
      o0[r] *= alpha[r];
      o1[r] *= alpha[r];
    }
    // P: C-layout -> A-layout through per-wave LDS
#pragma unroll
    for (int st = 0; st < 4; st++)
#pragma unroll
      for (int r = 0; r < 4; r++)
        pw[(quad * 4 + r) * 72 + st * 16 + l16] = f2bf(s[st][r]);
#pragma unroll
    for (int c = 0; c < 2; c++) {
      bf16x8 pf = *(const bf16x8*)&pw[l16 * 72 + c * 32 + quad * 8];
      bf16x8 vf0 = *(const bf16x8*)&vt[l16 * 72 + c * 32 + quad * 8];
      bf16x8 vf1 = *(const bf16x8*)&vt[(16 + l16) * 72 + c * 32 + quad * 8];
      o0 = __builtin_amdgcn_mfma_f32_16x16x32_bf16(pf, vf0, o0, 0, 0, 0);
      o1 = __builtin_amdgcn_mfma_f32_16x16x32_bf16(pf, vf1, o1, 0, 0, 0);
    }
  }
  // write partials (each wave its own region)
#pragma unroll
  for (int r = 0; r < 4; r++) {
    Om[wave][quad * 4 + r][l16] = o0[r];
    Om[wave][quad * 4 + r][16 + l16] = o1[r];
  }
  if (l16 == 0) {
#pragma unroll
    for (int r = 0; r < 4; r++) {
      Ml[wave][quad * 4 + r][0] = mrun[r];
      Ml[wave][quad * 4 + r][1] = lrun[r];
    }
  }
  __syncthreads();
  {
    const int q = tid >> 4;
    const int c2 = (tid & 15) * 2;
    const float m0 = Ml[0][q][0], m1 = Ml[1][q][0];
    const float m2 = Ml[2][q][0], m3 = Ml[3][q][0];
    const float M = fmaxf(fmaxf(m0, m1), fmaxf(m2, m3));
    const float a0 = __expf(m0 - M), a1 = __expf(m1 - M);
    const float a2 = __expf(m2 - M), a3 = __expf(m3 - M);
    const float lsum = a0 * Ml[0][q][1] + a1 * Ml[1][q][1] +
                       a2 * Ml[2][q][1] + a3 * Ml[3][q][1];
    const float s0 = a0 * Om[0][q][c2] + a1 * Om[1][q][c2] +
                     a2 * Om[2][q][c2] + a3 * Om[3][q][c2];
    const float s1 = a0 * Om[0][q][c2 + 1] + a1 * Om[1][q][c2 + 1] +
                     a2 * Om[2][q][c2 + 1] + a3 * Om[3][q][c2 + 1];
    const int qg = qt * 16 + q;
    if (qg < NQc) {
      const float inv = 1.f / lsum;
      float* dst = sa + ((size_t)(b * NQc + qg) * 256 + h * 32 + c2);
      dst[0] = s0 * inv;
      dst[1] = s1 * inv;
    }
  }
}

// ---------------------------------------------------------------------------
__global__ __launch_bounds__(256) void sample_k(
    const float* __restrict__ awlin, const float* __restrict__ off,
    const float* __restrict__ refp, const short* __restrict__ value,
    float* __restrict__ accout) {
  const int wid = blockIdx.x * 4 + (threadIdx.x >> 6);
  const int lane = threadIdx.x & 63;
  const int bq = wid >> 3, h = wid & 7;
  const int b = bq / NQc;
  const int l16 = lane & 15;

  float wraw = awlin[(size_t)bq * 128 + h * 16 + l16];
  float mx = wraw;
#pragma unroll
  for (int d = 1; d < 16; d <<= 1) mx = fmaxf(mx, __shfl_xor(mx, d));
  float e = __expf(wraw - mx), ssum = e;
#pragma unroll
  for (int d = 1; d < 16; d <<= 1) ssum += __shfl_xor(ssum, d);
  const float wnorm = e / ssum;

  const int ch = lane & 31, sub = lane >> 5;
  float facc = 0.f;
#pragma unroll
  for (int it = 0; it < 8; it++) {
    const int pt = it * 2 + sub;
    const float w = __shfl(wnorm, pt);
    const int l = pt >> 2;
    const int W = 128 >> l;
    const int start = (l == 0) ? 0 : (l == 1) ? 16384 : (l == 2) ? 20480 : 21504;
    const float offx = off[(size_t)bq * 256 + h * 32 + pt * 2];
    const float offy = off[(size_t)bq * 256 + h * 32 + pt * 2 + 1];
    const float rx = refp[(size_t)bq * 8 + l * 2];
    const float ry = refp[(size_t)bq * 8 + l * 2 + 1];
    const float x = rx * (float)W + offx - 0.5f;
    const float y = ry * (float)W + offy - 0.5f;
    const float x0f = floorf(x), y0f = floorf(y);
    const float wx = x - x0f, wy = y - y0f;
    const int x0 = (int)x0f, y0 = (int)y0f;
    const short* vb = value + ((size_t)b * Sc + start) * 256 + h * 32 + ch;
#pragma unroll
    for (int c4 = 0; c4 < 4; c4++) {
      const int dx = c4 & 1, dy = c4 >> 1;
      const int xi = x0 + dx, yi = y0 + dy;
      const bool valid = (xi >= 0) && (xi < W) && (yi >= 0) && (yi < W);
      const int xc = min(max(xi, 0), W - 1);
      const int yc = min(max(yi, 0), W - 1);
      const float gvv = bf2f(vb[(size_t)(yc * W + xc) * 256]);
      const float ww = (dx ? wx : 1.f - wx) * (dy ? wy : 1.f - wy);
      facc += valid ? w * ww * gvv : 0.f;
    }
  }
  facc += __shfl_xor(facc, 32);
  if (lane < 32) accout[(size_t)bq * 256 + h * 32 + ch] = facc;
}

// ---------------------------------------------------------------------------
extern "C" void kernel_launch(void* const* d_in, const int* in_sizes, int n_in,
                              void* d_out, int out_size, void* d_ws,
                              size_t ws_size, hipStream_t stream) {
  const float* tgt = (const float*)d_in[0];
  const float* query_pos = (const float*)d_in[1];
  const float* refp = (const float*)d_in[2];
  const float* memory = (const float*)d_in[3];
  const float* in_proj_w = (const float*)d_in[4];
  const float* in_proj_b = (const float*)d_in[5];
  const float* out_proj_w = (const float*)d_in[6];
  const float* out_proj_b = (const float*)d_in[7];
  const float* ln1_g = (const float*)d_in[8];
  const float* ln1_b = (const float*)d_in[9];
  const float* ln2_g = (const float*)d_in[10];
  const float* ln2_b = (const float*)d_in[11];
  const float* ln3_g = (const float*)d_in[12];
  const float* ln3_b = (const float*)d_in[13];
  const float* vproj_w = (const float*)d_in[14];
  const float* vproj_b = (const float*)d_in[15];
  const float* off_w = (const float*)d_in[16];
  const float* off_b = (const float*)d_in[17];
  const float* aw_w = (const float*)d_in[18];
  const float* aw_b = (const float*)d_in[19];
  const float* oproj_w = (const float*)d_in[20];
  const float* oproj_b = (const float*)d_in[21];
  const float* lin1_w = (const float*)d_in[22];
  const float* lin1_b = (const float*)d_in[23];
  const float* lin2_w = (const float*)d_in[24];
  const float* lin2_b = (const float*)d_in[25];
  const unsigned char* mem_mask = (const unsigned char*)d_in[27];
  float* out = (float*)d_out;

  float* ws = (float*)d_ws;
  float* qkbuf = ws + 921600;     // [3600][512]
  float* vbuf = ws + 2764800;     // [3600][256]
  float* sa = ws + 3686400;
  float* tgt2 = ws + 5529600;
  float* query = ws + 6451200;
  float* offb = ws + 7372800;
  float* awlin = ws + 8294400;
  float* accb = ws + 8755200;
  float* tgt3 = ws + 9676800;
  float* ff1 = ws + 10598400;     // [3600][1024]
  short* valueBf = (short*)(ws + 14284800);  // 22282240 shorts
  short* wbase = valueBf + 22282240;
  short* inT = wbase + 0;         // [8][768][32]
  short* outT = wbase + 196608;   // [8][256][32]
  short* vT = wbase + 262144;
  short* oT = wbase + 327680;
  short* lin1T = wbase + 393216;  // [8][1024][32]
  short* lin2T = wbase + 655360;  // [32][256][32]

  pack_all_k<<<896, 256, 0, stream>>>(in_proj_w, inT, out_proj_w, outT,
                                      vproj_w, vT, oproj_w, oT,
                                      lin1_w, lin1T, lin2_w, lin2T);

  // fused q|k|v projection (q,k add query_pos; v plain tgt)
  gemmv_k<2, 0, 32><<<113 * 3, 256, 0, stream>>>(
      tgt, query_pos, inT, in_proj_b, qkbuf, vbuf, M1, 768, 256,
      nullptr, nullptr, nullptr, nullptr, nullptr, nullptr);
  attn_k<<<Bc * Hc * QT16, 256, 0, stream>>>(qkbuf, vbuf, sa);
  // out_proj + residual + LN2, and query = tgt2 + query_pos
  gemmv_k<3, 0, 32><<<113, 256, 0, stream>>>(
      sa, nullptr, outT, out_proj_b, tgt2, nullptr, M1, 256, 256,
      nullptr, ln2_g, ln2_b, tgt, query_pos, query);
  // value = memory @ vproj -> bf16 (masked rows zeroed)
  gemmv_k<1, 0, 64><<<1360, 256, 0, stream>>>(
      memory, nullptr, vT, vproj_b, valueBf, nullptr, Bc * Sc, 256, 256,
      mem_mask, nullptr, nullptr, nullptr, nullptr, nullptr);
  // off + aw in one launch (exact fp32: sampler-amplified path)
  gemm32_offaw_k<<<342, 256, 0, stream>>>(query, off_w, off_b, offb, aw_w, aw_b, awlin);
  sample_k<<<Bc * NQc * Hc / 4, 256, 0, stream>>>(awlin, offb, refp, valueBf, accb);
  // oproj + residual + LN1
  gemmv_k<3, 0, 32><<<113, 256, 0, stream>>>(
      accb, nullptr, oT, oproj_b, tgt3, nullptr, M1, 256, 256,
      nullptr, ln1_g, ln1_b, tgt2, nullptr, nullptr);
  // FFN
  gemmv_k<0, 1, 64><<<57 * 4, 256, 0, stream>>>(
      tgt3, nullptr, lin1T, lin1_b, ff1, nullptr, M1, 1024, 256,
      nullptr, nullptr, nullptr, nullptr, nullptr, nullptr);
  gemmv_k<3, 0, 32><<<113, 256, 0, stream>>>(
      ff1, nullptr, lin2T, lin2_b, out, nullptr, M1, 256, 1024,
      nullptr, ln3_g, ln3_b, tgt3, nullptr, nullptr);
}

// Round 7
// 427.260 us; speedup vs baseline: 1.5369x; 1.1009x over previous
//
#include <hip/hip_runtime.h>
#include <hip/hip_bf16.h>

typedef __attribute__((ext_vector_type(8))) short bf16x8;
typedef __attribute__((ext_vector_type(4))) short bf16x4;
typedef __attribute__((ext_vector_type(4))) float f32x4;

#define DEV static __device__ __forceinline__

constexpr int Bc = 4, NQc = 900, Hc = 8, Sc = 21760;
constexpr int M1 = Bc * NQc;           // 3600
constexpr int NQT = (NQc + 63) / 64;   // 15 key tiles of 64
constexpr int QT16 = (NQc + 15) / 16;  // 57 query tiles of 16
constexpr int QKo = Bc * Hc * 960 * 32;  // 983040: size of one [b][h][960][32] buf

DEV short f2bf(float f) {
  union { __hip_bfloat16 h; short s; } u;
  u.h = __float2bfloat16(f);
  return u.s;
}
DEV float bf2f(short s) {
  union { short s; __hip_bfloat16 h; } u;
  u.s = s;
  return __bfloat162float(u.h);
}

// ---------------------------------------------------------------------------
// Pack W[K][N] f32 -> k-tiled bf16 [K/32][N][32]
DEV void pack_body(const float* W, short* Wt, int K, int N, int t) {
  int n = t % N;
  int k4 = (t / N) * 4;
  bf16x4 o;
  o[0] = f2bf(W[(size_t)(k4 + 0) * N + n]);
  o[1] = f2bf(W[(size_t)(k4 + 1) * N + n]);
  o[2] = f2bf(W[(size_t)(k4 + 2) * N + n]);
  o[3] = f2bf(W[(size_t)(k4 + 3) * N + n]);
  *(bf16x4*)&Wt[((size_t)(k4 >> 5) * N + n) * 32 + (k4 & 31)] = o;
}

__global__ __launch_bounds__(256) void pack_all_k(
    const float* w0, short* t0, const float* w1, short* t1,
    const float* w2, short* t2, const float* w3, short* t3,
    const float* w4, short* t4, const float* w5, short* t5) {
  int t = blockIdx.x * 256 + threadIdx.x;
  if (t < 49152) pack_body(w0, t0, 256, 768, t);
  else if (t < 65536) pack_body(w1, t1, 256, 256, t - 49152);
  else if (t < 81920) pack_body(w2, t2, 256, 256, t - 65536);
  else if (t < 98304) pack_body(w3, t3, 256, 256, t - 81920);
  else if (t < 163840) pack_body(w4, t4, 256, 1024, t - 98304);
  else pack_body(w5, t5, 1024, 256, t - 163840);
}

// ---------------------------------------------------------------------------
// Unified MT x 256N bf16 MFMA GEMM, K-step 32, distance-2 register prefetch.
// MODE 0: f32 out (+ACT relu)
// MODE 3: LN epilogue (N=256): Cv = LN(resid + A@W + b)*g + beta [+ out2=+qpos]
// MODE 4: qkv: bn0 -> qbf (scaled bf16 [bh][960][32]), bn1 -> kbf (same),
//         bn2 -> vtbf (bf16 [bh][15][32ch][64key]); q,k add A2.
template <int MODE, int ACT, int MT>
__global__ __launch_bounds__(256) void gemmv_k(
    const float* __restrict__ A, const float* __restrict__ A2,
    const short* __restrict__ Wt, const float* __restrict__ bias,
    void* __restrict__ Cv, float* __restrict__ C2, int M, int N, int K,
    const unsigned char* __restrict__ rowmask, const float* __restrict__ g,
    const float* __restrict__ beta, const float* __restrict__ resid,
    const float* __restrict__ qpos, float* __restrict__ out2) {
  constexpr int IT = MT / 16;
  __shared__ short As[MT * 40];
  __shared__ short Ws[256 * 40];
  const int nb = N >> 8;
  const int mb = blockIdx.x / nb, bn = blockIdx.x - mb * nb;
  const int tid = threadIdx.x;
  const int lane = tid & 63, wave = tid >> 6;
  const int l16 = lane & 15, quad = lane >> 4;
  const int sr = (MT == 64) ? (tid >> 2) : (tid >> 3);
  const int sk = (MT == 64) ? ((tid & 3) * 8) : ((tid & 7) * 4);
  const int arow = mb * MT + sr;
  const bool aval = arow < M;
  const bool useA2 = (MODE == 4) ? (bn < 2) : (A2 != nullptr);
  const float* ap = A + (size_t)arow * K + sk;
  const float* ap2 = (A2 ? A2 : A) + (size_t)arow * K + sk;
  const short* wp = Wt + (size_t)(bn * 256 + tid) * 32;
  const size_t wstep = (size_t)N * 32;
  const int KT = K >> 5;

  f32x4 acc[IT][4] = {};
  float4 pa0[2] = {}, pa1[2] = {};
  bf16x8 pw[2][4];

  auto loadA = [&](int s, int it) {
    if (aval) {
      const float* p = ap + it * 32;
      pa0[s] = *(const float4*)p;
      if constexpr (MT == 64) pa1[s] = *(const float4*)(p + 4);
      if (useA2) {
        const float* p2 = ap2 + it * 32;
        float4 q0 = *(const float4*)p2;
        pa0[s].x += q0.x; pa0[s].y += q0.y; pa0[s].z += q0.z; pa0[s].w += q0.w;
        if constexpr (MT == 64) {
          float4 q1 = *(const float4*)(p2 + 4);
          pa1[s].x += q1.x; pa1[s].y += q1.y; pa1[s].z += q1.z; pa1[s].w += q1.w;
        }
      }
    }
  };
  auto loadW = [&](int s, int it) {
    const short* p = wp + (size_t)it * wstep;
    pw[s][0] = *(const bf16x8*)(p + 0);
    pw[s][1] = *(const bf16x8*)(p + 8);
    pw[s][2] = *(const bf16x8*)(p + 16);
    pw[s][3] = *(const bf16x8*)(p + 24);
  };
  auto stage = [&](int s) {
    if constexpr (MT == 64) {
      bf16x8 t;
      t[0] = f2bf(pa0[s].x); t[1] = f2bf(pa0[s].y); t[2] = f2bf(pa0[s].z); t[3] = f2bf(pa0[s].w);
      t[4] = f2bf(pa1[s].x); t[5] = f2bf(pa1[s].y); t[6] = f2bf(pa1[s].z); t[7] = f2bf(pa1[s].w);
      *(bf16x8*)&As[sr * 40 + sk] = t;
    } else {
      bf16x4 t;
      t[0] = f2bf(pa0[s].x); t[1] = f2bf(pa0[s].y); t[2] = f2bf(pa0[s].z); t[3] = f2bf(pa0[s].w);
      *(bf16x4*)&As[sr * 40 + sk] = t;
    }
    short* wd = &Ws[tid * 40];
    *(bf16x8*)(wd + 0) = pw[s][0];
    *(bf16x8*)(wd + 8) = pw[s][1];
    *(bf16x8*)(wd + 16) = pw[s][2];
    *(bf16x8*)(wd + 24) = pw[s][3];
  };
  auto compute = [&]() {
    bf16x8 af[IT], bfr[4];
#pragma unroll
    for (int i = 0; i < IT; i++)
      af[i] = *(const bf16x8*)&As[(i * 16 + l16) * 40 + quad * 8];
#pragma unroll
    for (int j = 0; j < 4; j++)
      bfr[j] = *(const bf16x8*)&Ws[(wave * 64 + j * 16 + l16) * 40 + quad * 8];
#pragma unroll
    for (int i = 0; i < IT; i++)
#pragma unroll
      for (int j = 0; j < 4; j++)
        acc[i][j] = __builtin_amdgcn_mfma_f32_16x16x32_bf16(af[i], bfr[j], acc[i][j], 0, 0, 0);
  };

  loadA(0, 0); loadW(0, 0);
  loadA(1, 1); loadW(1, 1);
  for (int it = 0; it < KT; it += 2) {
    stage(0);
    __syncthreads();
    if (it + 2 < KT) { loadA(0, it + 2); loadW(0, it + 2); }
    compute();
    __syncthreads();
    stage(1);
    __syncthreads();
    if (it + 3 < KT) { loadA(1, it + 3); loadW(1, it + 3); }
    compute();
    __syncthreads();
  }

  // ---- epilogues ----
  if constexpr (MODE == 4) {
    short* base = (short*)Cv;
#pragma unroll
    for (int i = 0; i < IT; i++)
#pragma unroll
      for (int r = 0; r < 4; r++) {
        const int m = mb * MT + i * 16 + quad * 4 + r;
        if (m >= M) continue;
        const int b = m / NQc, q = m - b * NQc;
#pragma unroll
        for (int j = 0; j < 4; j++) {
          const int cl = wave * 64 + j * 16 + l16;
          const float v = acc[i][j][r] + bias[bn * 256 + cl];
          const int h = cl >> 5, ch = cl & 31;
          if (bn == 0) {
            base[((size_t)(b * 8 + h) * 960 + q) * 32 + ch] =
                f2bf(v * 0.17677669529663687f);
          } else if (bn == 1) {
            base[QKo + ((size_t)(b * 8 + h) * 960 + q) * 32 + ch] = f2bf(v);
          } else {
            base[2 * QKo + ((((size_t)(b * 8 + h) * 15 + (q >> 6)) * 32 + ch) * 64 + (q & 63))] = f2bf(v);
          }
        }
      }
  } else if constexpr (MODE == 0) {
#pragma unroll
    for (int i = 0; i < IT; i++)
#pragma unroll
      for (int j = 0; j < 4; j++) {
        const int cl = wave * 64 + j * 16 + l16;
        const int col = bn * 256 + cl;
        const float bb = bias[col];
#pragma unroll
        for (int r = 0; r < 4; r++) {
          const int m = mb * MT + i * 16 + quad * 4 + r;
          if (m < M) {
            float v = acc[i][j][r] + bb;
            if (ACT == 1) v = fmaxf(v, 0.f);
            ((float*)Cv)[(size_t)m * N + col] = v;
          }
        }
      }
  } else {  // MODE 3: fused LayerNorm epilogue (N==256)
#pragma unroll
    for (int j = 0; j < 4; j++) {
      const int cl = wave * 64 + j * 16 + l16;
      const float bb = bias[cl];
#pragma unroll
      for (int i = 0; i < IT; i++)
#pragma unroll
        for (int r = 0; r < 4; r++) {
          const int m = mb * MT + i * 16 + quad * 4 + r;
          const float rs = (m < M) ? resid[(size_t)m * 256 + cl] : 0.f;
          acc[i][j][r] += bb + rs;
        }
    }
    float2* pr = (float2*)As;
#pragma unroll
    for (int i = 0; i < IT; i++)
#pragma unroll
      for (int r = 0; r < 4; r++) {
        float s = 0.f, q = 0.f;
#pragma unroll
        for (int j = 0; j < 4; j++) {
          s += acc[i][j][r];
          q += acc[i][j][r] * acc[i][j][r];
        }
#pragma unroll
        for (int d = 1; d < 16; d <<= 1) {
          s += __shfl_xor(s, d);
          q += __shfl_xor(q, d);
        }
        if (l16 == 0) pr[(i * 16 + quad * 4 + r) * 4 + wave] = make_float2(s, q);
      }
    __syncthreads();
#pragma unroll
    for (int i = 0; i < IT; i++)
#pragma unroll
      for (int r = 0; r < 4; r++) {
        const int ml = i * 16 + quad * 4 + r;
        float2 p0 = pr[ml * 4 + 0], p1 = pr[ml * 4 + 1];
        float2 p2 = pr[ml * 4 + 2], p3 = pr[ml * 4 + 3];
        const float sum = p0.x + p1.x + p2.x + p3.x;
        const float sq = p0.y + p1.y + p2.y + p3.y;
        const float mean = sum * (1.f / 256.f);
        const float var = sq * (1.f / 256.f) - mean * mean;
        const float rstd = rsqrtf(var + 1e-5f);
        const int m = mb * MT + ml;
        if (m < M) {
#pragma unroll
          for (int j = 0; j < 4; j++) {
            const int cl = wave * 64 + j * 16 + l16;
            const float o = (acc[i][j][r] - mean) * rstd * g[cl] + beta[cl];
            ((float*)Cv)[(size_t)m * 256 + cl] = o;
            if (out2) out2[(size_t)m * 256 + cl] = o + qpos[(size_t)m * 256 + cl];
          }
        }
      }
  }
}

// ---------------------------------------------------------------------------
// Value projection GEMM: 128M x 256N tile, K=256, distance-1 prefetch,
// bf16 out + rowmask.
__global__ __launch_bounds__(256) void gemm_val_k(
    const float* __restrict__ A, const short* __restrict__ Wt,
    const float* __restrict__ bias, short* __restrict__ Cv, int M,
    const unsigned char* __restrict__ rowmask) {
  __shared__ short As[128 * 40];
  __shared__ short Ws[256 * 40];
  const int mb = blockIdx.x;
  const int tid = threadIdx.x;
  const int lane = tid & 63, wave = tid >> 6;
  const int l16 = lane & 15, quad = lane >> 4;
  const int sr = tid >> 1, sk = (tid & 1) * 16;
  const int arow = mb * 128 + sr;
  const bool aval = arow < M;
  const float* ap = A + (size_t)arow * 256 + sk;
  const short* wp = Wt + (size_t)tid * 32;

  f32x4 acc[8][4] = {};
  float4 pa[4];
  bf16x8 pwr[4];

  auto loadA = [&](int it) {
    if (aval) {
#pragma unroll
      for (int i = 0; i < 4; i++) pa[i] = *(const float4*)(ap + it * 32 + i * 4);
    }
  };
  auto loadW = [&](int it) {
    const short* p = wp + (size_t)it * (256 * 32);
    pwr[0] = *(const bf16x8*)(p + 0);
    pwr[1] = *(const bf16x8*)(p + 8);
    pwr[2] = *(const bf16x8*)(p + 16);
    pwr[3] = *(const bf16x8*)(p + 24);
  };

  loadA(0); loadW(0);
  for (int it = 0; it < 8; ++it) {
    {
      bf16x8 t0, t1;
      t0[0] = f2bf(pa[0].x); t0[1] = f2bf(pa[0].y); t0[2] = f2bf(pa[0].z); t0[3] = f2bf(pa[0].w);
      t0[4] = f2bf(pa[1].x); t0[5] = f2bf(pa[1].y); t0[6] = f2bf(pa[1].z); t0[7] = f2bf(pa[1].w);
      t1[0] = f2bf(pa[2].x); t1[1] = f2bf(pa[2].y); t1[2] = f2bf(pa[2].z); t1[3] = f2bf(pa[2].w);
      t1[4] = f2bf(pa[3].x); t1[5] = f2bf(pa[3].y); t1[6] = f2bf(pa[3].z); t1[7] = f2bf(pa[3].w);
      *(bf16x8*)&As[sr * 40 + sk] = t0;
      *(bf16x8*)&As[sr * 40 + sk + 8] = t1;
      short* wd = &Ws[tid * 40];
      *(bf16x8*)(wd + 0) = pwr[0];
      *(bf16x8*)(wd + 8) = pwr[1];
      *(bf16x8*)(wd + 16) = pwr[2];
      *(bf16x8*)(wd + 24) = pwr[3];
    }
    __syncthreads();
    if (it + 1 < 8) { loadA(it + 1); loadW(it + 1); }
    bf16x8 af[8], bfr[4];
#pragma unroll
    for (int i = 0; i < 8; i++)
      af[i] = *(const bf16x8*)&As[(i * 16 + l16) * 40 + quad * 8];
#pragma unroll
    for (int j = 0; j < 4; j++)
      bfr[j] = *(const bf16x8*)&Ws[(wave * 64 + j * 16 + l16) * 40 + quad * 8];
#pragma unroll
    for (int i = 0; i < 8; i++)
#pragma unroll
      for (int j = 0; j < 4; j++)
        acc[i][j] = __builtin_amdgcn_mfma_f32_16x16x32_bf16(af[i], bfr[j], acc[i][j], 0, 0, 0);
    __syncthreads();
  }
#pragma unroll
  for (int i = 0; i < 8; i++)
#pragma unroll
    for (int j = 0; j < 4; j++) {
      const int cl = wave * 64 + j * 16 + l16;
      const float bb = bias[cl];
#pragma unroll
      for (int r = 0; r < 4; r++) {
        const int m = mb * 128 + i * 16 + quad * 4 + r;
        if (m < M) {
          float v = acc[i][j][r] + bb;
          if (rowmask[m]) v = 0.f;
          Cv[(size_t)m * 256 + cl] = f2bf(v);
        }
      }
    }
}

// ---------------------------------------------------------------------------
// Exact fp32 GEMM body (off/aw: sampler-amplified precision path)
DEV void gemm32_body(const float* __restrict__ A, const float* __restrict__ W,
                     const float* __restrict__ bias, float* __restrict__ C,
                     int M, int N, int K, int bid) {
  __shared__ float Asf[16][64];
  __shared__ float Bsf[16][68];
  const int nb = N >> 6;
  const int bm = bid / nb, bn = bid % nb;
  const int tid = threadIdx.x;
  const int tm = tid >> 4, tn = tid & 15;
  float acc[4][4] = {};

  for (int k0 = 0; k0 < K; k0 += 16) {
    {
      const int m = tid >> 2, kk = (tid & 3) * 4;
      const int row = bm * 64 + m;
      float4 v = (row < M) ? *(const float4*)(A + (size_t)row * K + k0 + kk)
                           : make_float4(0.f, 0.f, 0.f, 0.f);
      Asf[kk + 0][m] = v.x; Asf[kk + 1][m] = v.y;
      Asf[kk + 2][m] = v.z; Asf[kk + 3][m] = v.w;
    }
    {
      const int kk = tid >> 4, n = (tid & 15) * 4;
      float4 v = *(const float4*)(W + (size_t)(k0 + kk) * N + bn * 64 + n);
      *(float4*)&Bsf[kk][n] = v;
    }
    __syncthreads();
#pragma unroll
    for (int kk = 0; kk < 16; kk++) {
      float a[4], b[4];
#pragma unroll
      for (int i = 0; i < 4; i++) a[i] = Asf[kk][tm * 4 + i];
#pragma unroll
      for (int j = 0; j < 4; j++) b[j] = Bsf[kk][tn * 4 + j];
#pragma unroll
      for (int i = 0; i < 4; i++)
#pragma unroll
        for (int j = 0; j < 4; j++) acc[i][j] = fmaf(a[i], b[j], acc[i][j]);
    }
    __syncthreads();
  }
#pragma unroll
  for (int i = 0; i < 4; i++) {
    const int row = bm * 64 + tm * 4 + i;
    if (row >= M) continue;
#pragma unroll
    for (int j = 0; j < 4; j++) {
      const int col = bn * 64 + tn * 4 + j;
      C[(size_t)row * N + col] = acc[i][j] + bias[col];
    }
  }
}

__global__ __launch_bounds__(256) void gemm32_offaw_k(
    const float* __restrict__ query, const float* __restrict__ off_w,
    const float* __restrict__ off_b, float* __restrict__ offb,
    const float* __restrict__ aw_w, const float* __restrict__ aw_b,
    float* __restrict__ awlin) {
  if (blockIdx.x < 228)
    gemm32_body(query, off_w, off_b, offb, M1, 256, 256, blockIdx.x);
  else
    gemm32_body(query, aw_w, aw_b, awlin, M1, 128, 256, blockIdx.x - 228);
}

// ---------------------------------------------------------------------------
// Flash attention from pre-packed bf16 buffers. Block = (b,h,16 queries),
// 2 waves split key tiles even/odd. Hot loop: coalesced bf16x8 global loads
// (Q,K from [bh][960][32], V^T from [bh][15][32][64]) straight into MFMA —
// no f2bf, no V staging, no barriers. Single merge barrier at end.
__global__ __launch_bounds__(128) void attn_k(const short* __restrict__ qbf,
                                              const short* __restrict__ kbf,
                                              const short* __restrict__ vtbf,
                                              float* __restrict__ sa) {
  __shared__ short Pb[2][16 * 72];
  __shared__ float Om[2][16][32];
  __shared__ float Ml[2][16][2];
  const int bid = blockIdx.x;
  const int qt = bid % QT16, bh = bid / QT16;
  const int tid = threadIdx.x, lane = tid & 63, wave = tid >> 6;
  const int l16 = lane & 15, quad = lane >> 4;

  const int q_local = min(qt * 16 + l16, NQc - 1);
  const bf16x8 qf = *(const bf16x8*)&qbf[((size_t)bh * 960 + q_local) * 32 + quad * 8];
  const short* kb = kbf + (size_t)bh * 960 * 32;
  const short* vb = vtbf + (size_t)bh * 15 * 32 * 64;

  f32x4 o0 = {}, o1 = {};
  float mrun[4] = {-1e30f, -1e30f, -1e30f, -1e30f};
  float lrun[4] = {0.f, 0.f, 0.f, 0.f};
  short* pw = Pb[wave];

  for (int kt = wave; kt < NQT; kt += 2) {
    const int k0 = kt * 64;
    f32x4 s[4];
#pragma unroll
    for (int st = 0; st < 4; st++) {
      const int key = k0 + st * 16 + l16;
      const bf16x8 kf = *(const bf16x8*)&kb[(size_t)key * 32 + quad * 8];
      f32x4 z = {};
      s[st] = __builtin_amdgcn_mfma_f32_16x16x32_bf16(qf, kf, z, 0, 0, 0);
      if (key >= NQc) { s[st][0] = -1e30f; s[st][1] = -1e30f; s[st][2] = -1e30f; s[st][3] = -1e30f; }
    }
    float mnew[4], alpha[4];
#pragma unroll
    for (int r = 0; r < 4; r++) {
      float mx = fmaxf(fmaxf(s[0][r], s[1][r]), fmaxf(s[2][r], s[3][r]));
#pragma unroll
      for (int d = 1; d < 16; d <<= 1) mx = fmaxf(mx, __shfl_xor(mx, d));
      mnew[r] = fmaxf(mrun[r], mx);
      alpha[r] = __expf(mrun[r] - mnew[r]);
      mrun[r] = mnew[r];
    }
    float tsum[4] = {0.f, 0.f, 0.f, 0.f};
#pragma unroll
    for (int st = 0; st < 4; st++)
#pragma unroll
      for (int r = 0; r < 4; r++) {
        float p = __expf(s[st][r] - mnew[r]);
        s[st][r] = p;
        tsum[r] += p;
      }
#pragma unroll
    for (int r = 0; r < 4; r++) {
      float t = tsum[r];
#pragma unroll
      for (int d = 1; d < 16; d <<= 1) t += __shfl_xor(t, d);
      lrun[r] = lrun[r] * alpha[r] + t;
      o0[r] *= alpha[r];
      o1[r] *= alpha[r];
    }
    // P: C-layout -> A-layout via per-wave LDS (wave-local, no barrier)
#pragma unroll
    for (int st = 0; st < 4; st++)
#pragma unroll
      for (int r = 0; r < 4; r++)
        pw[(quad * 4 + r) * 72 + st * 16 + l16] = f2bf(s[st][r]);
    const short* vt = vb + kt * (32 * 64);
#pragma unroll
    for (int c = 0; c < 2; c++) {
      bf16x8 pf = *(const bf16x8*)&pw[l16 * 72 + c * 32 + quad * 8];
      bf16x8 vf0 = *(const bf16x8*)&vt[(size_t)l16 * 64 + c * 32 + quad * 8];
      bf16x8 vf1 = *(const bf16x8*)&vt[(size_t)(16 + l16) * 64 + c * 32 + quad * 8];
      o0 = __builtin_amdgcn_mfma_f32_16x16x32_bf16(pf, vf0, o0, 0, 0, 0);
      o1 = __builtin_amdgcn_mfma_f32_16x16x32_bf16(pf, vf1, o1, 0, 0, 0);
    }
  }
#pragma unroll
  for (int r = 0; r < 4; r++) {
    Om[wave][quad * 4 + r][l16] = o0[r];
    Om[wave][quad * 4 + r][16 + l16] = o1[r];
  }
  if (l16 == 0) {
#pragma unroll
    for (int r = 0; r < 4; r++) {
      Ml[wave][quad * 4 + r][0] = mrun[r];
      Ml[wave][quad * 4 + r][1] = lrun[r];
    }
  }
  __syncthreads();
  {
    const int q = tid >> 3;
    const int c4 = (tid & 7) * 4;
    const float m0 = Ml[0][q][0], m1 = Ml[1][q][0];
    const float M = fmaxf(m0, m1);
    const float a0 = __expf(m0 - M), a1 = __expf(m1 - M);
    const float lsum = a0 * Ml[0][q][1] + a1 * Ml[1][q][1];
    const int qg = qt * 16 + q;
    if (qg < NQc) {
      const float inv = 1.f / lsum;
      float4 o;
      o.x = (a0 * Om[0][q][c4 + 0] + a1 * Om[1][q][c4 + 0]) * inv;
      o.y = (a0 * Om[0][q][c4 + 1] + a1 * Om[1][q][c4 + 1]) * inv;
      o.z = (a0 * Om[0][q][c4 + 2] + a1 * Om[1][q][c4 + 2]) * inv;
      o.w = (a0 * Om[0][q][c4 + 3] + a1 * Om[1][q][c4 + 3]) * inv;
      const int b = bh >> 3, h = bh & 7;
      *(float4*)&sa[(size_t)(b * NQc + qg) * 256 + h * 32 + c4] = o;
    }
  }
}

// ---------------------------------------------------------------------------
__global__ __launch_bounds__(256) void sample_k(
    const float* __restrict__ awlin, const float* __restrict__ off,
    const float* __restrict__ refp, const short* __restrict__ value,
    float* __restrict__ accout) {
  const int wid = blockIdx.x * 4 + (threadIdx.x >> 6);
  const int lane = threadIdx.x & 63;
  const int bq = wid >> 3, h = wid & 7;
  const int b = bq / NQc;
  const int l16 = lane & 15;

  float wraw = awlin[(size_t)bq * 128 + h * 16 + l16];
  float mx = wraw;
#pragma unroll
  for (int d = 1; d < 16; d <<= 1) mx = fmaxf(mx, __shfl_xor(mx, d));
  float e = __expf(wraw - mx), ssum = e;
#pragma unroll
  for (int d = 1; d < 16; d <<= 1) ssum += __shfl_xor(ssum, d);
  const float wnorm = e / ssum;

  const int ch = lane & 31, sub = lane >> 5;
  float facc = 0.f;
#pragma unroll
  for (int it = 0; it < 8; it++) {
    const int pt = it * 2 + sub;
    const float w = __shfl(wnorm, pt);
    const int l = pt >> 2;
    const int W = 128 >> l;
    const int start = (l == 0) ? 0 : (l == 1) ? 16384 : (l == 2) ? 20480 : 21504;
    const float offx = off[(size_t)bq * 256 + h * 32 + pt * 2];
    const float offy = off[(size_t)bq * 256 + h * 32 + pt * 2 + 1];
    const float rx = refp[(size_t)bq * 8 + l * 2];
    const float ry = refp[(size_t)bq * 8 + l * 2 + 1];
    const float x = rx * (float)W + offx - 0.5f;
    const float y = ry * (float)W + offy - 0.5f;
    const float x0f = floorf(x), y0f = floorf(y);
    const float wx = x - x0f, wy = y - y0f;
    const int x0 = (int)x0f, y0 = (int)y0f;
    const short* vbp = value + ((size_t)b * Sc + start) * 256 + h * 32 + ch;
#pragma unroll
    for (int c4 = 0; c4 < 4; c4++) {
      const int dx = c4 & 1, dy = c4 >> 1;
      const int xi = x0 + dx, yi = y0 + dy;
      const bool valid = (xi >= 0) && (xi < W) && (yi >= 0) && (yi < W);
      const int xc = min(max(xi, 0), W - 1);
      const int yc = min(max(yi, 0), W - 1);
      const float gvv = bf2f(vbp[(size_t)(yc * W + xc) * 256]);
      const float ww = (dx ? wx : 1.f - wx) * (dy ? wy : 1.f - wy);
      facc += valid ? w * ww * gvv : 0.f;
    }
  }
  facc += __shfl_xor(facc, 32);
  if (lane < 32) accout[(size_t)bq * 256 + h * 32 + ch] = facc;
}

// ---------------------------------------------------------------------------
extern "C" void kernel_launch(void* const* d_in, const int* in_sizes, int n_in,
                              void* d_out, int out_size, void* d_ws,
                              size_t ws_size, hipStream_t stream) {
  const float* tgt = (const float*)d_in[0];
  const float* query_pos = (const float*)d_in[1];
  const float* refp = (const float*)d_in[2];
  const float* memory = (const float*)d_in[3];
  const float* in_proj_w = (const float*)d_in[4];
  const float* in_proj_b = (const float*)d_in[5];
  const float* out_proj_w = (const float*)d_in[6];
  const float* out_proj_b = (const float*)d_in[7];
  const float* ln1_g = (const float*)d_in[8];
  const float* ln1_b = (const float*)d_in[9];
  const float* ln2_g = (const float*)d_in[10];
  const float* ln2_b = (const float*)d_in[11];
  const float* ln3_g = (const float*)d_in[12];
  const float* ln3_b = (const float*)d_in[13];
  const float* vproj_w = (const float*)d_in[14];
  const float* vproj_b = (const float*)d_in[15];
  const float* off_w = (const float*)d_in[16];
  const float* off_b = (const float*)d_in[17];
  const float* aw_w = (const float*)d_in[18];
  const float* aw_b = (const float*)d_in[19];
  const float* oproj_w = (const float*)d_in[20];
  const float* oproj_b = (const float*)d_in[21];
  const float* lin1_w = (const float*)d_in[22];
  const float* lin1_b = (const float*)d_in[23];
  const float* lin2_w = (const float*)d_in[24];
  const float* lin2_b = (const float*)d_in[25];
  const unsigned char* mem_mask = (const unsigned char*)d_in[27];
  float* out = (float*)d_out;

  float* ws = (float*)d_ws;
  short* qbf = (short*)(ws + 921600);  // qbf|kbf|vtbf: 3*983040 shorts
  float* sa = ws + 3686400;
  float* tgt2 = ws + 5529600;
  float* query = ws + 6451200;
  float* offb = ws + 7372800;
  float* awlin = ws + 8294400;
  float* accb = ws + 8755200;
  float* tgt3 = ws + 9676800;
  float* ff1 = ws + 10598400;     // [3600][1024]
  short* valueBf = (short*)(ws + 14284800);  // 22282240 shorts
  short* wbase = valueBf + 22282240;
  short* inT = wbase + 0;         // [8][768][32]
  short* outT = wbase + 196608;
  short* vT = wbase + 262144;
  short* oT = wbase + 327680;
  short* lin1T = wbase + 393216;  // [8][1024][32]
  short* lin2T = wbase + 655360;  // [32][256][32]

  pack_all_k<<<896, 256, 0, stream>>>(in_proj_w, inT, out_proj_w, outT,
                                      vproj_w, vT, oproj_w, oT,
                                      lin1_w, lin1T, lin2_w, lin2T);

  // fused q|k|v projection -> bf16 MFMA-layout buffers
  gemmv_k<4, 0, 32><<<113 * 3, 256, 0, stream>>>(
      tgt, query_pos, inT, in_proj_b, qbf, nullptr, M1, 768, 256,
      nullptr, nullptr, nullptr, nullptr, nullptr, nullptr);
  attn_k<<<Bc * Hc * QT16, 128, 0, stream>>>(qbf, qbf + QKo, qbf + 2 * QKo, sa);
  // out_proj + residual + LN2, and query = tgt2 + query_pos
  gemmv_k<3, 0, 32><<<113, 256, 0, stream>>>(
      sa, nullptr, outT, out_proj_b, tgt2, nullptr, M1, 256, 256,
      nullptr, ln2_g, ln2_b, tgt, query_pos, query);
  // value = memory @ vproj -> bf16
  gemm_val_k<<<680, 256, 0, stream>>>(memory, vT, vproj_b, valueBf, Bc * Sc, mem_mask);
  // off + aw (exact fp32: sampler-amplified path)
  gemm32_offaw_k<<<342, 256, 0, stream>>>(query, off_w, off_b, offb, aw_w, aw_b, awlin);
  sample_k<<<Bc * NQc * Hc / 4, 256, 0, stream>>>(awlin, offb, refp, valueBf, accb);
  // oproj + residual + LN1
  gemmv_k<3, 0, 32><<<113, 256, 0, stream>>>(
      accb, nullptr, oT, oproj_b, tgt3, nullptr, M1, 256, 256,
      nullptr, ln1_g, ln1_b, tgt2, nullptr, nullptr);
  // FFN
  gemmv_k<0, 1, 64><<<57 * 4, 256, 0, stream>>>(
      tgt3, nullptr, lin1T, lin1_b, ff1, nullptr, M1, 1024, 256,
      nullptr, nullptr, nullptr, nullptr, nullptr, nullptr);
  gemmv_k<3, 0, 32><<<113, 256, 0, stream>>>(
      ff1, nullptr, lin2T, lin2_b, out, nullptr, M1, 256, 1024,
      nullptr, ln3_g, ln3_b, tgt3, nullptr, nullptr);
}